// Round 3
// baseline (4991.964 us; speedup 1.0000x reference)
//
#include <hip/hip_runtime.h>
#include <hip/hip_bf16.h>

#define N_NODES 20000
#define N_EDGES 320000
#define BATCH 2
#define IN_DIM 32
#define HID 64
#define HEADS 4
#define OUT_DIM 8
#define ROWS (N_NODES * BATCH) /* 40000 */
#define SLOPE 0.2f

typedef __hip_bfloat16 bf16;

// ---- workspace layout (float slots) ----
#define WS_FLAG 0
#define WS_X    64          /* 2,560,000 floats */
#define WS_FT   2560064     /* 10,240,000 bf16 = 5,120,000 float slots */
#define WS_EL   7680064     /* 160,000 */
#define WS_ER   7840064     /* 160,000 */
#define WS_WSUM 8000064     /* 160,000 */
#define WS_AGG  8160064     /* 10,240,000 */
#define WS_END  18400064    /* 73.6 MB */

__device__ __forceinline__ float us2f(unsigned short u) {
    union { unsigned int i; float f; } z; z.i = ((unsigned int)u) << 16; return z.f;
}
__device__ __forceinline__ unsigned short f2us(float f) {
    bf16 b = __float2bfloat16(f);
    return *(unsigned short*)&b;
}
// dual-dtype input load: isbf ? bf16 : fp32
__device__ __forceinline__ float ld(const void* p, int i, int isbf) {
    if (isbf) return us2f(((const unsigned short*)p)[i]);
    return ((const float*)p)[i];
}

// Decide whether float inputs are bf16 or fp32 by inspecting even 16-bit halves of h.
// fp32: halves are mantissa bits -> "exponent" field uniform -> ~20% in [100,150].
// bf16: halves are real bf16 numbers from N(0,1) -> ~100% in [100,150].
__global__ __launch_bounds__(256) void k_sniff(const void* __restrict__ h, int* __restrict__ flag) {
    __shared__ int cnt;
    if (threadIdx.x == 0) cnt = 0;
    __syncthreads();
    const unsigned short* u = (const unsigned short*)h;
    unsigned short v = u[2 * threadIdx.x];
    int ef = (v >> 7) & 0xFF;
    if (ef >= 100 && ef <= 150) atomicAdd(&cnt, 1);
    __syncthreads();
    if (threadIdx.x == 0) flag[0] = (cnt >= 192) ? 1 : 0;
}

// x[row=n*2+b][0..63] = h[b][n][:] @ W_enc + b_enc
__global__ __launch_bounds__(256) void k_enc(const void* __restrict__ h,
                                             const void* __restrict__ W,
                                             const void* __restrict__ bias,
                                             float* __restrict__ x,
                                             const int* __restrict__ flag) {
    const int isbf = flag[0];
    __shared__ float sW[IN_DIM * HID];
    __shared__ float sB[HID];
    int t = threadIdx.x;
    for (int i = t; i < IN_DIM * HID; i += 256) sW[i] = ld(W, i, isbf);
    if (t < HID) sB[t] = ld(bias, t, isbf);
    __syncthreads();
    int row = blockIdx.x * 4 + (t >> 6);
    int col = t & 63;
    if (row >= ROWS) return;
    int n = row >> 1, b = row & 1;
    size_t hbase = (size_t)(b * N_NODES + n) * IN_DIM;
    float acc = sB[col];
#pragma unroll
    for (int k = 0; k < IN_DIM; k++) acc += ld(h, hbase + k, isbf) * sW[k * HID + col];
    x[(size_t)row * HID + col] = acc;
}

// ft[row][0..255] = x[row] @ W_gat (stored bf16); el/er[row][h] = ft_head . a_l/a_r
__global__ __launch_bounds__(256) void k_gat_proj(const float* __restrict__ x,
                                                  const void* __restrict__ Wg,
                                                  const void* __restrict__ al,
                                                  const void* __restrict__ ar,
                                                  unsigned short* __restrict__ ftb,
                                                  float* __restrict__ el,
                                                  float* __restrict__ er,
                                                  const int* __restrict__ flag) {
    const int isbf = flag[0];
    __shared__ unsigned short sW[HID * 256];   // bf16 bits, 32 KB
    __shared__ float sAl[256], sAr[256];
    __shared__ float sX[8][HID];
    int t = threadIdx.x;
    for (int i = t; i < HID * 256; i += 256)
        sW[i] = isbf ? ((const unsigned short*)Wg)[i] : f2us(((const float*)Wg)[i]);
    sAl[t] = ld(al, t, isbf);
    sAr[t] = ld(ar, t, isbf);
    int row0 = blockIdx.x * 8;
    for (int i = t; i < 8 * HID; i += 256) {
        int r = row0 + (i >> 6);
        sX[i >> 6][i & 63] = (r < ROWS) ? x[(size_t)r * HID + (i & 63)] : 0.f;
    }
    __syncthreads();
    int head = t >> 6, dd = t & 63;
    float va = sAl[t], vb = sAr[t];
    for (int rr = 0; rr < 8; rr++) {
        int row = row0 + rr;
        if (row >= ROWS) return;
        float acc = 0.f;
#pragma unroll
        for (int k = 0; k < HID; k++) acc += sX[rr][k] * us2f(sW[k * 256 + t]);
        ftb[(size_t)row * 256 + t] = f2us(acc);
        float cl = acc * va, cr = acc * vb;
#pragma unroll
        for (int off = 32; off; off >>= 1) {
            cl += __shfl_down(cl, off);
            cr += __shfl_down(cr, off);
        }
        if (dd == 0) {
            el[row * HEADS + head] = cl;
            er[row * HEADS + head] = cr;
        }
    }
}

// per edge: wsum[dst] += exp(leakyrelu(el[src]+er[dst])) for 8 (b,h) combos
__global__ __launch_bounds__(256) void k_edge1(const int* __restrict__ src,
                                               const int* __restrict__ dst,
                                               const float* __restrict__ el,
                                               const float* __restrict__ er,
                                               float* __restrict__ wsum) {
    int e = blockIdx.x * 256 + threadIdx.x;
    if (e >= N_EDGES) return;
    int s = src[e], d = dst[e];
#pragma unroll
    for (int i = 0; i < 8; i++) {
        float v = el[s * 8 + i] + er[d * 8 + i];
        v = v > 0.f ? v : SLOPE * v;
        v = fminf(v, 60.f);
        atomicAdd(&wsum[d * 8 + i], __expf(v));
    }
}

// one wave per (edge, b); lane handles 4 features. agg[dst] += alpha * ft[src]
__global__ __launch_bounds__(256) void k_edge2(const int* __restrict__ src,
                                               const int* __restrict__ dst,
                                               const float* __restrict__ el,
                                               const float* __restrict__ er,
                                               const float* __restrict__ wsum,
                                               const unsigned short* __restrict__ ftb,
                                               float* __restrict__ agg) {
    unsigned gid = blockIdx.x * 256u + threadIdx.x;
    unsigned w = gid >> 6;
    int l = gid & 63;
    if (w >= 2u * N_EDGES) return;
    unsigned e = w >> 1;
    int b = w & 1;
    int s = src[e], d = dst[e];
    int hh = l >> 4;
    int i = b * 4 + hh;
    float v = el[s * 8 + i] + er[d * 8 + i];
    v = v > 0.f ? v : SLOPE * v;
    v = fminf(v, 60.f);
    float alpha = __expf(v) / wsum[d * 8 + i];
    const ushort4* fp = (const ushort4*)(ftb + (size_t)(s * 2 + b) * 256);
    ushort4 q = fp[l];
    float* ap = agg + (size_t)(d * 2 + b) * 256 + 4 * l;
    atomicAdd(ap + 0, alpha * us2f(q.x));
    atomicAdd(ap + 1, alpha * us2f(q.y));
    atomicAdd(ap + 2, alpha * us2f(q.z));
    atomicAdd(ap + 3, alpha * us2f(q.w));
}

// x = elu( mean_h(agg + b_gat) + x @ W_res + b_res )   (in-place, row-local)
__global__ __launch_bounds__(256) void k_update(float* __restrict__ x,
                                                const float* __restrict__ agg,
                                                const void* __restrict__ bg,
                                                const void* __restrict__ Wr,
                                                const void* __restrict__ br,
                                                const int* __restrict__ flag) {
    const int isbf = flag[0];
    __shared__ float sW[HID * HID];  // 16 KB
    __shared__ float sX[4][HID];
    __shared__ float sB[HID], sG[256];
    int t = threadIdx.x;
    for (int i = t; i < HID * HID; i += 256) sW[i] = ld(Wr, i, isbf);
    sG[t] = ld(bg, t, isbf);
    if (t < HID) sB[t] = ld(br, t, isbf);
    int row0 = blockIdx.x * 4;
    int rr = t >> 6, col = t & 63;
    int row = row0 + rr;
    sX[rr][col] = (row < ROWS) ? x[(size_t)row * HID + col] : 0.f;
    __syncthreads();
    if (row >= ROWS) return;
    float acc = sB[col];
#pragma unroll
    for (int k = 0; k < HID; k++) acc += sX[rr][k] * sW[k * HID + col];
    float m = 0.f;
#pragma unroll
    for (int hh = 0; hh < HEADS; hh++)
        m += agg[(size_t)row * 256 + hh * 64 + col] + sG[hh * 64 + col];
    acc += 0.25f * m;
    x[(size_t)row * HID + col] = acc > 0.f ? acc : expm1f(acc);
}

// out[b][n][o] = x[row=n*2+b] @ W_dec + b_dec ; output dtype matches input dtype
__global__ __launch_bounds__(256) void k_dec(const float* __restrict__ x,
                                             const void* __restrict__ Wd,
                                             const void* __restrict__ bd,
                                             void* __restrict__ out,
                                             const int* __restrict__ flag) {
    const int isbf = flag[0];
    __shared__ float sW[HID * OUT_DIM];
    __shared__ float sB[OUT_DIM];
    int t = threadIdx.x;
    for (int i = t; i < HID * OUT_DIM; i += 256) sW[i] = ld(Wd, i, isbf);
    if (t < OUT_DIM) sB[t] = ld(bd, t, isbf);
    __syncthreads();
    int gid = blockIdx.x * 256 + t;
    if (gid >= ROWS * OUT_DIM) return;
    int row = gid >> 3, o = gid & 7;
    int n = row >> 1, b = row & 1;
    float acc = sB[o];
#pragma unroll
    for (int k = 0; k < HID; k++) acc += x[(size_t)row * HID + k] * sW[k * OUT_DIM + o];
    size_t oi = (size_t)(b * N_NODES + n) * OUT_DIM + o;
    if (isbf) ((unsigned short*)out)[oi] = f2us(acc);
    else      ((float*)out)[oi] = acc;
}

extern "C" void kernel_launch(void* const* d_in, const int* in_sizes, int n_in,
                              void* d_out, int out_size, void* d_ws, size_t ws_size,
                              hipStream_t stream) {
    const void* h     = d_in[0];
    const int*  ei    = (const int*)d_in[1];
    const void* W_enc = d_in[2];
    const void* b_enc = d_in[3];
    const void* W_gat = d_in[4];
    const void* a_l   = d_in[5];
    const void* a_r   = d_in[6];
    const void* b_gat = d_in[7];
    const void* W_res = d_in[8];
    const void* b_res = d_in[9];
    const void* W_dec = d_in[10];
    const void* b_dec = d_in[11];

    float* ws = (float*)d_ws;
    int*   flag = (int*)(ws + WS_FLAG);
    float* x    = ws + WS_X;
    unsigned short* ftb = (unsigned short*)(ws + WS_FT);
    float* el   = ws + WS_EL;
    float* er   = ws + WS_ER;
    float* wsum = ws + WS_WSUM;
    float* agg  = ws + WS_AGG;

    const int* src = ei;
    const int* dst = ei + N_EDGES;

    k_sniff<<<1, 256, 0, stream>>>(h, flag);
    k_enc<<<ROWS / 4, 256, 0, stream>>>(h, W_enc, b_enc, x, flag);

    for (int r = 0; r < 2; r++) {
        k_gat_proj<<<ROWS / 8, 256, 0, stream>>>(x, W_gat, a_l, a_r, ftb, el, er, flag);
        hipMemsetAsync(wsum, 0, (size_t)(160000 + 10240000) * sizeof(float), stream);
        k_edge1<<<(N_EDGES + 255) / 256, 256, 0, stream>>>(src, dst, el, er, wsum);
        k_edge2<<<(2 * N_EDGES * 64) / 256, 256, 0, stream>>>(src, dst, el, er, wsum, ftb, agg);
        k_update<<<ROWS / 4, 256, 0, stream>>>(x, agg, b_gat, W_res, b_res, flag);
    }
    k_dec<<<(ROWS * OUT_DIM + 255) / 256, 256, 0, stream>>>(x, W_dec, b_dec, d_out, flag);
}

// Round 4
// 760.971 us; speedup vs baseline: 6.5600x; 6.5600x over previous
//
#include <hip/hip_runtime.h>
#include <hip/hip_bf16.h>

#define N_NODES 20000
#define N_EDGES 320000
#define BATCH 2
#define IN_DIM 32
#define HID 64
#define HEADS 4
#define OUT_DIM 8
#define ROWS (N_NODES * BATCH) /* 40000 */
#define SLOPE 0.2f

typedef __hip_bfloat16 bf16;

// ---- workspace layout (float slots) ----
#define WS_FLAG 0
#define WS_X        64        /* 2,560,000 floats */
#define WS_FT       2560064   /* 10,240,000 bf16 = 5,120,000 float slots */
#define WS_EL       7680064   /* 160,000 */
#define WS_ER       7840064   /* 160,000 */
#define WS_AGGM     8000064   /* 2,560,000 : head-meaned agg (+b_gat) */
#define WS_DEG      10560064  /* 20,032 ints */
#define WS_ROWSTART 10580096  /* 20,032 ints (20001 used) */
#define WS_CUR      10600128  /* 20,032 ints */
#define WS_CSRC     10620160  /* 320,000 ints: src node of each dst-bucketed edge */
#define WS_END      10940160  /* 43.8 MB */

__device__ __forceinline__ float us2f(unsigned short u) {
    union { unsigned int i; float f; } z; z.i = ((unsigned int)u) << 16; return z.f;
}
__device__ __forceinline__ unsigned short f2us(float f) {
    bf16 b = __float2bfloat16(f);
    return *(unsigned short*)&b;
}
__device__ __forceinline__ float ld(const void* p, int i, int isbf) {
    if (isbf) return us2f(((const unsigned short*)p)[i]);
    return ((const float*)p)[i];
}

// bf16-vs-fp32 input sniffer (see R2 notes): even 16-bit halves of fp32 data have
// uniform-random "exponent" fields; real bf16 from N(0,.01..1) lands in [100,150].
__global__ __launch_bounds__(256) void k_sniff(const void* __restrict__ h, int* __restrict__ flag) {
    __shared__ int cnt;
    if (threadIdx.x == 0) cnt = 0;
    __syncthreads();
    const unsigned short* u = (const unsigned short*)h;
    unsigned short v = u[2 * threadIdx.x];
    int ef = (v >> 7) & 0xFF;
    if (ef >= 100 && ef <= 150) atomicAdd(&cnt, 1);
    __syncthreads();
    if (threadIdx.x == 0) flag[0] = (cnt >= 192) ? 1 : 0;
}

// ---- CSR build: histogram -> scan -> scatter ----
__global__ __launch_bounds__(256) void k_hist(const int* __restrict__ dst, int* __restrict__ deg) {
    int e = blockIdx.x * 256 + threadIdx.x;
    if (e < N_EDGES) atomicAdd(&deg[dst[e]], 1);
}

__global__ __launch_bounds__(1024) void k_scan(const int* __restrict__ deg,
                                               int* __restrict__ rowstart,
                                               int* __restrict__ cursor) {
    __shared__ int ssum[1024];
    int t = threadIdx.x;
    int base = t * 20;
    int local[20];
    int s = 0;
#pragma unroll
    for (int i = 0; i < 20; i++) {
        int v = (base + i < N_NODES) ? deg[base + i] : 0;
        local[i] = s;
        s += v;
    }
    ssum[t] = s;
    __syncthreads();
    for (int off = 1; off < 1024; off <<= 1) {
        int v = (t >= off) ? ssum[t - off] : 0;
        __syncthreads();
        if (t >= off) ssum[t] += v;
        __syncthreads();
    }
    int prev = (t == 0) ? 0 : ssum[t - 1];
#pragma unroll
    for (int i = 0; i < 20; i++) {
        if (base + i < N_NODES) {
            int v = prev + local[i];
            rowstart[base + i] = v;
            cursor[base + i] = v;
        }
    }
    if (t == 1023) rowstart[N_NODES] = ssum[1023];
}

__global__ __launch_bounds__(256) void k_scatter(const int* __restrict__ src,
                                                 const int* __restrict__ dst,
                                                 int* __restrict__ cursor,
                                                 int* __restrict__ csrc) {
    int e = blockIdx.x * 256 + threadIdx.x;
    if (e >= N_EDGES) return;
    int pos = atomicAdd(&cursor[dst[e]], 1);
    csrc[pos] = src[e];
}

// x[row=n*2+b][0..63] = h[b][n][:] @ W_enc + b_enc
__global__ __launch_bounds__(256) void k_enc(const void* __restrict__ h,
                                             const void* __restrict__ W,
                                             const void* __restrict__ bias,
                                             float* __restrict__ x,
                                             const int* __restrict__ flag) {
    const int isbf = flag[0];
    __shared__ float sW[IN_DIM * HID];
    __shared__ float sB[HID];
    int t = threadIdx.x;
    for (int i = t; i < IN_DIM * HID; i += 256) sW[i] = ld(W, i, isbf);
    if (t < HID) sB[t] = ld(bias, t, isbf);
    __syncthreads();
    int row = blockIdx.x * 4 + (t >> 6);
    int col = t & 63;
    if (row >= ROWS) return;
    int n = row >> 1, b = row & 1;
    size_t hbase = (size_t)(b * N_NODES + n) * IN_DIM;
    float acc = sB[col];
#pragma unroll
    for (int k = 0; k < IN_DIM; k++) acc += ld(h, hbase + k, isbf) * sW[k * HID + col];
    x[(size_t)row * HID + col] = acc;
}

// ft[row][0..255] = x[row] @ W_gat (stored bf16); el/er[row][h] = ft_head . a_l/a_r
__global__ __launch_bounds__(256) void k_gat_proj(const float* __restrict__ x,
                                                  const void* __restrict__ Wg,
                                                  const void* __restrict__ al,
                                                  const void* __restrict__ ar,
                                                  unsigned short* __restrict__ ftb,
                                                  float* __restrict__ el,
                                                  float* __restrict__ er,
                                                  const int* __restrict__ flag) {
    const int isbf = flag[0];
    __shared__ unsigned short sW[HID * 256];   // bf16 bits, 32 KB
    __shared__ float sAl[256], sAr[256];
    __shared__ float sX[8][HID];
    int t = threadIdx.x;
    for (int i = t; i < HID * 256; i += 256)
        sW[i] = isbf ? ((const unsigned short*)Wg)[i] : f2us(((const float*)Wg)[i]);
    sAl[t] = ld(al, t, isbf);
    sAr[t] = ld(ar, t, isbf);
    int row0 = blockIdx.x * 8;
    for (int i = t; i < 8 * HID; i += 256) {
        int r = row0 + (i >> 6);
        sX[i >> 6][i & 63] = (r < ROWS) ? x[(size_t)r * HID + (i & 63)] : 0.f;
    }
    __syncthreads();
    int head = t >> 6, dd = t & 63;
    float va = sAl[t], vb = sAr[t];
    for (int rr = 0; rr < 8; rr++) {
        int row = row0 + rr;
        if (row >= ROWS) return;
        float acc = 0.f;
#pragma unroll
        for (int k = 0; k < HID; k++) acc += sX[rr][k] * us2f(sW[k * 256 + t]);
        ftb[(size_t)row * 256 + t] = f2us(acc);
        float cl = acc * va, cr = acc * vb;
#pragma unroll
        for (int off = 32; off; off >>= 1) {
            cl += __shfl_down(cl, off);
            cr += __shfl_down(cr, off);
        }
        if (dd == 0) {
            el[row * HEADS + head] = cl;
            er[row * HEADS + head] = cr;
        }
    }
}

// One block per (dst node, batch). Gather over in-edges via CSR:
// aggm[dst*2+b][c] = mean_h( (sum_e w_e ft[src_e][h,c]) / (sum_e w_e) + bg[h,c] )
__global__ __launch_bounds__(256) void k_agg(const int* __restrict__ rowstart,
                                             const int* __restrict__ csrc,
                                             const float* __restrict__ el,
                                             const float* __restrict__ er,
                                             const unsigned short* __restrict__ ftb,
                                             const void* __restrict__ bg,
                                             float* __restrict__ aggm,
                                             const int* __restrict__ flag) {
    const int isbf = flag[0];
    int blk = blockIdx.x;
    int n = blk >> 1, b = blk & 1;
    int t = threadIdx.x;
    int h = t >> 6;
    int i = b * 4 + h;
    float erd = er[n * 8 + i];
    int beg = rowstart[n], end = rowstart[n + 1];
    float acc = 0.f, wsum = 0.f;
    for (int p = beg; p < end; p++) {
        int s = csrc[p];
        float v = el[s * 8 + i] + erd;
        v = v > 0.f ? v : SLOPE * v;
        float w = __expf(fminf(v, 60.f));
        wsum += w;
        acc += w * us2f(ftb[(size_t)(s * 2 + b) * 256 + t]);
    }
    float val = (end > beg) ? (acc / wsum) : 0.f;
    val += ld(bg, t, isbf);
    __shared__ float red[256];
    red[t] = val;
    __syncthreads();
    if (t < 64) {
        float m = 0.25f * (red[t] + red[t + 64] + red[t + 128] + red[t + 192]);
        aggm[(size_t)(n * 2 + b) * HID + t] = m;
    }
}

// x = elu( aggm + x @ W_res + b_res )   (in-place, row-local)
__global__ __launch_bounds__(256) void k_update(float* __restrict__ x,
                                                const float* __restrict__ aggm,
                                                const void* __restrict__ Wr,
                                                const void* __restrict__ br,
                                                const int* __restrict__ flag) {
    const int isbf = flag[0];
    __shared__ float sW[HID * HID];  // 16 KB
    __shared__ float sX[4][HID];
    __shared__ float sB[HID];
    int t = threadIdx.x;
    for (int i = t; i < HID * HID; i += 256) sW[i] = ld(Wr, i, isbf);
    if (t < HID) sB[t] = ld(br, t, isbf);
    int row0 = blockIdx.x * 4;
    int rr = t >> 6, col = t & 63;
    int row = row0 + rr;
    sX[rr][col] = (row < ROWS) ? x[(size_t)row * HID + col] : 0.f;
    __syncthreads();
    if (row >= ROWS) return;
    float acc = sB[col] + aggm[(size_t)row * HID + col];
#pragma unroll
    for (int k = 0; k < HID; k++) acc += sX[rr][k] * sW[k * HID + col];
    x[(size_t)row * HID + col] = acc > 0.f ? acc : expm1f(acc);
}

// out[b][n][o] = x[row=n*2+b] @ W_dec + b_dec ; output dtype follows input dtype
__global__ __launch_bounds__(256) void k_dec(const float* __restrict__ x,
                                             const void* __restrict__ Wd,
                                             const void* __restrict__ bd,
                                             void* __restrict__ out,
                                             const int* __restrict__ flag) {
    const int isbf = flag[0];
    __shared__ float sW[HID * OUT_DIM];
    __shared__ float sB[OUT_DIM];
    int t = threadIdx.x;
    for (int i = t; i < HID * OUT_DIM; i += 256) sW[i] = ld(Wd, i, isbf);
    if (t < OUT_DIM) sB[t] = ld(bd, t, isbf);
    __syncthreads();
    int gid = blockIdx.x * 256 + t;
    if (gid >= ROWS * OUT_DIM) return;
    int row = gid >> 3, o = gid & 7;
    int n = row >> 1, b = row & 1;
    float acc = sB[o];
#pragma unroll
    for (int k = 0; k < HID; k++) acc += x[(size_t)row * HID + k] * sW[k * OUT_DIM + o];
    size_t oi = (size_t)(b * N_NODES + n) * OUT_DIM + o;
    if (isbf) ((unsigned short*)out)[oi] = f2us(acc);
    else      ((float*)out)[oi] = acc;
}

extern "C" void kernel_launch(void* const* d_in, const int* in_sizes, int n_in,
                              void* d_out, int out_size, void* d_ws, size_t ws_size,
                              hipStream_t stream) {
    const void* h     = d_in[0];
    const int*  ei    = (const int*)d_in[1];
    const void* W_enc = d_in[2];
    const void* b_enc = d_in[3];
    const void* W_gat = d_in[4];
    const void* a_l   = d_in[5];
    const void* a_r   = d_in[6];
    const void* b_gat = d_in[7];
    const void* W_res = d_in[8];
    const void* b_res = d_in[9];
    const void* W_dec = d_in[10];
    const void* b_dec = d_in[11];

    float* ws = (float*)d_ws;
    int*   flag     = (int*)(ws + WS_FLAG);
    float* x        = ws + WS_X;
    unsigned short* ftb = (unsigned short*)(ws + WS_FT);
    float* el       = ws + WS_EL;
    float* er       = ws + WS_ER;
    float* aggm     = ws + WS_AGGM;
    int*   deg      = (int*)(ws + WS_DEG);
    int*   rowstart = (int*)(ws + WS_ROWSTART);
    int*   cursor   = (int*)(ws + WS_CUR);
    int*   csrc     = (int*)(ws + WS_CSRC);

    const int* src = ei;
    const int* dst = ei + N_EDGES;

    k_sniff<<<1, 256, 0, stream>>>(h, flag);
    k_enc<<<ROWS / 4, 256, 0, stream>>>(h, W_enc, b_enc, x, flag);

    // CSR build (dst-bucketed src list)
    hipMemsetAsync(deg, 0, N_NODES * sizeof(int), stream);
    k_hist<<<(N_EDGES + 255) / 256, 256, 0, stream>>>(dst, deg);
    k_scan<<<1, 1024, 0, stream>>>(deg, rowstart, cursor);
    k_scatter<<<(N_EDGES + 255) / 256, 256, 0, stream>>>(src, dst, cursor, csrc);

    for (int r = 0; r < 2; r++) {
        k_gat_proj<<<ROWS / 8, 256, 0, stream>>>(x, W_gat, a_l, a_r, ftb, el, er, flag);
        k_agg<<<ROWS, 256, 0, stream>>>(rowstart, csrc, el, er, ftb, b_gat, aggm, flag);
        k_update<<<ROWS / 4, 256, 0, stream>>>(x, aggm, W_res, b_res, flag);
    }
    k_dec<<<(ROWS * OUT_DIM + 255) / 256, 256, 0, stream>>>(x, W_dec, b_dec, d_out, flag);
}

// Round 5
// 592.345 us; speedup vs baseline: 8.4275x; 1.2847x over previous
//
#include <hip/hip_runtime.h>
#include <hip/hip_bf16.h>

#define N_NODES 20000
#define N_EDGES 320000
#define BATCH 2
#define IN_DIM 32
#define HID 64
#define HEADS 4
#define OUT_DIM 8
#define ROWS (N_NODES * BATCH) /* 40000 */
#define SLOPE 0.2f

typedef __hip_bfloat16 bf16;

// ---- workspace layout (float slots) ----
#define WS_FLAG 0
#define WS_X        64        /* 2,560,000 floats */
#define WS_FT       2560064   /* 10,240,000 bf16 = 5,120,000 float slots */
#define WS_EL       7680064   /* 160,000 */
#define WS_ER       7840064   /* 160,000 */
#define WS_AGGM     8000064   /* 2,560,000 : head-meaned agg (+b_gat) */
#define WS_DEG      10560064  /* 20,032 ints */
#define WS_ROWSTART 10580096  /* 20,032 ints (20001 used) */
#define WS_CUR      10600128  /* 20,032 ints */
#define WS_CSRC     10620160  /* 320,000 ints */
#define WS_CDST     10940160  /* 320,000 ints */
#define WS_WEXP     11260160  /* 2,560,000 floats */
#define WS_END      13820160  /* 55.3 MB */

__device__ __forceinline__ float us2f(unsigned short u) {
    union { unsigned int i; float f; } z; z.i = ((unsigned int)u) << 16; return z.f;
}
__device__ __forceinline__ float u2f_lo(unsigned int u) {
    union { unsigned int i; float f; } z; z.i = u << 16; return z.f;
}
__device__ __forceinline__ float u2f_hi(unsigned int u) {
    union { unsigned int i; float f; } z; z.i = u & 0xffff0000u; return z.f;
}
__device__ __forceinline__ unsigned short f2us(float f) {
    bf16 b = __float2bfloat16(f);
    return *(unsigned short*)&b;
}
__device__ __forceinline__ float ld(const void* p, int i, int isbf) {
    if (isbf) return us2f(((const unsigned short*)p)[i]);
    return ((const float*)p)[i];
}
__device__ __forceinline__ float lrexp(float v) {
    v = v > 0.f ? v : SLOPE * v;
    return __expf(fminf(v, 60.f));
}

// bf16-vs-fp32 input sniffer (see R2 notes).
__global__ __launch_bounds__(256) void k_sniff(const void* __restrict__ h, int* __restrict__ flag) {
    __shared__ int cnt;
    if (threadIdx.x == 0) cnt = 0;
    __syncthreads();
    const unsigned short* u = (const unsigned short*)h;
    unsigned short v = u[2 * threadIdx.x];
    int ef = (v >> 7) & 0xFF;
    if (ef >= 100 && ef <= 150) atomicAdd(&cnt, 1);
    __syncthreads();
    if (threadIdx.x == 0) flag[0] = (cnt >= 192) ? 1 : 0;
}

// ---- CSR build: histogram -> scan -> scatter ----
__global__ __launch_bounds__(256) void k_hist(const int* __restrict__ dst, int* __restrict__ deg) {
    int e = blockIdx.x * 256 + threadIdx.x;
    if (e < N_EDGES) atomicAdd(&deg[dst[e]], 1);
}

__global__ __launch_bounds__(1024) void k_scan(const int* __restrict__ deg,
                                               int* __restrict__ rowstart,
                                               int* __restrict__ cursor) {
    __shared__ int ssum[1024];
    int t = threadIdx.x;
    int base = t * 20;
    int local[20];
    int s = 0;
#pragma unroll
    for (int i = 0; i < 20; i++) {
        int v = (base + i < N_NODES) ? deg[base + i] : 0;
        local[i] = s;
        s += v;
    }
    ssum[t] = s;
    __syncthreads();
    for (int off = 1; off < 1024; off <<= 1) {
        int v = (t >= off) ? ssum[t - off] : 0;
        __syncthreads();
        if (t >= off) ssum[t] += v;
        __syncthreads();
    }
    int prev = (t == 0) ? 0 : ssum[t - 1];
#pragma unroll
    for (int i = 0; i < 20; i++) {
        if (base + i < N_NODES) {
            int v = prev + local[i];
            rowstart[base + i] = v;
            cursor[base + i] = v;
        }
    }
    if (t == 1023) rowstart[N_NODES] = ssum[1023];
}

__global__ __launch_bounds__(256) void k_scatter(const int* __restrict__ src,
                                                 const int* __restrict__ dst,
                                                 int* __restrict__ cursor,
                                                 int* __restrict__ csrc,
                                                 int* __restrict__ cdst) {
    int e = blockIdx.x * 256 + threadIdx.x;
    if (e >= N_EDGES) return;
    int d = dst[e];
    int pos = atomicAdd(&cursor[d], 1);
    csrc[pos] = src[e];
    cdst[pos] = d;
}

// x[row=n*2+b][0..63] = h[b][n][:] @ W_enc + b_enc
__global__ __launch_bounds__(256) void k_enc(const void* __restrict__ h,
                                             const void* __restrict__ W,
                                             const void* __restrict__ bias,
                                             float* __restrict__ x,
                                             const int* __restrict__ flag) {
    const int isbf = flag[0];
    __shared__ float sW[IN_DIM * HID];
    __shared__ float sB[HID];
    int t = threadIdx.x;
    for (int i = t; i < IN_DIM * HID; i += 256) sW[i] = ld(W, i, isbf);
    if (t < HID) sB[t] = ld(bias, t, isbf);
    __syncthreads();
    int row = blockIdx.x * 4 + (t >> 6);
    int col = t & 63;
    if (row >= ROWS) return;
    int n = row >> 1, b = row & 1;
    size_t hbase = (size_t)(b * N_NODES + n) * IN_DIM;
    float acc = sB[col];
#pragma unroll
    for (int k = 0; k < IN_DIM; k++) acc += ld(h, hbase + k, isbf) * sW[k * HID + col];
    x[(size_t)row * HID + col] = acc;
}

// ft[row][0..255] = x[row] @ W_gat (stored bf16); el/er[row][h] = ft_head . a_l/a_r
// LDS weights packed 2 bf16 per u32 (k even/odd) -> ds_read_b32 in inner loop.
__global__ __launch_bounds__(256) void k_gat_proj(const float* __restrict__ x,
                                                  const void* __restrict__ Wg,
                                                  const void* __restrict__ al,
                                                  const void* __restrict__ ar,
                                                  unsigned short* __restrict__ ftb,
                                                  float* __restrict__ el,
                                                  float* __restrict__ er,
                                                  const int* __restrict__ flag) {
    const int isbf = flag[0];
    __shared__ unsigned int sW2[32 * 256];   // 32 KB
    __shared__ float sAl[256], sAr[256];
    __shared__ float sX[8][HID];
    int t = threadIdx.x;
    for (int i = t; i < 32 * 256; i += 256) {
        int kk = i >> 8;                     // column == t
        unsigned short lo = isbf ? ((const unsigned short*)Wg)[(2 * kk) * 256 + t]
                                 : f2us(((const float*)Wg)[(2 * kk) * 256 + t]);
        unsigned short hi = isbf ? ((const unsigned short*)Wg)[(2 * kk + 1) * 256 + t]
                                 : f2us(((const float*)Wg)[(2 * kk + 1) * 256 + t]);
        sW2[i] = (unsigned int)lo | ((unsigned int)hi << 16);
    }
    sAl[t] = ld(al, t, isbf);
    sAr[t] = ld(ar, t, isbf);
    int row0 = blockIdx.x * 8;
    for (int i = t; i < 8 * HID; i += 256) {
        int r = row0 + (i >> 6);
        sX[i >> 6][i & 63] = (r < ROWS) ? x[(size_t)r * HID + (i & 63)] : 0.f;
    }
    __syncthreads();
    int head = t >> 6, dd = t & 63;
    float va = sAl[t], vb = sAr[t];
    for (int rr = 0; rr < 8; rr++) {
        int row = row0 + rr;
        if (row >= ROWS) return;
        float acc = 0.f;
#pragma unroll
        for (int kk = 0; kk < 32; kk++) {
            unsigned int u = sW2[kk * 256 + t];
            acc += sX[rr][2 * kk] * u2f_lo(u) + sX[rr][2 * kk + 1] * u2f_hi(u);
        }
        ftb[(size_t)row * 256 + t] = f2us(acc);
        float cl = acc * va, cr = acc * vb;
#pragma unroll
        for (int off = 32; off; off >>= 1) {
            cl += __shfl_down(cl, off);
            cr += __shfl_down(cr, off);
        }
        if (dd == 0) {
            el[row * HEADS + head] = cl;
            er[row * HEADS + head] = cr;
        }
    }
}

// per CSR position: wexp[p][i] = exp(leakyrelu(el[src][i] + er[dst][i])), i = b*4+h
__global__ __launch_bounds__(256) void k_wexp(const int* __restrict__ csrc,
                                              const int* __restrict__ cdst,
                                              const float* __restrict__ el,
                                              const float* __restrict__ er,
                                              float* __restrict__ wexp) {
    int p = blockIdx.x * 256 + threadIdx.x;
    if (p >= N_EDGES) return;
    int s = csrc[p], d = cdst[p];
    float4 ea = ((const float4*)el)[s * 2];
    float4 eb = ((const float4*)el)[s * 2 + 1];
    float4 ra = ((const float4*)er)[d * 2];
    float4 rb = ((const float4*)er)[d * 2 + 1];
    float4 wa, wb;
    wa.x = lrexp(ea.x + ra.x); wa.y = lrexp(ea.y + ra.y);
    wa.z = lrexp(ea.z + ra.z); wa.w = lrexp(ea.w + ra.w);
    wb.x = lrexp(eb.x + rb.x); wb.y = lrexp(eb.y + rb.y);
    wb.z = lrexp(eb.z + rb.z); wb.w = lrexp(eb.w + rb.w);
    ((float4*)wexp)[p * 2] = wa;
    ((float4*)wexp)[p * 2 + 1] = wb;
}

// One block per dst node, both batches. thread t: head h=t>>6, col t.
// aggm[(n,b)][c] = mean_h( (sum_e w ft[src_e,b][h,c]) / (sum_e w) + bg[h,c] )
__global__ __launch_bounds__(256) void k_agg(const int* __restrict__ rowstart,
                                             const int* __restrict__ csrc,
                                             const float* __restrict__ wexp,
                                             const unsigned short* __restrict__ ftb,
                                             const void* __restrict__ bg,
                                             float* __restrict__ aggm,
                                             const int* __restrict__ flag) {
    const int isbf = flag[0];
    int n = blockIdx.x;
    int t = threadIdx.x;
    int h = t >> 6;
    int beg = rowstart[n], end = rowstart[n + 1];
    float acc0 = 0.f, acc1 = 0.f, ws0 = 0.f, ws1 = 0.f;
    int p = beg;
    for (; p + 1 < end; p += 2) {
        int s0 = csrc[p], s1 = csrc[p + 1];
        float wa0 = wexp[p * 8 + h];
        float wb0 = wexp[p * 8 + 4 + h];
        float wa1 = wexp[(p + 1) * 8 + h];
        float wb1 = wexp[(p + 1) * 8 + 4 + h];
        unsigned short q0a = ftb[(size_t)s0 * 512 + t];
        unsigned short q0b = ftb[(size_t)s0 * 512 + 256 + t];
        unsigned short q1a = ftb[(size_t)s1 * 512 + t];
        unsigned short q1b = ftb[(size_t)s1 * 512 + 256 + t];
        acc0 += wa0 * us2f(q0a) + wa1 * us2f(q1a);
        acc1 += wb0 * us2f(q0b) + wb1 * us2f(q1b);
        ws0 += wa0 + wa1;
        ws1 += wb0 + wb1;
    }
    if (p < end) {
        int s0 = csrc[p];
        float wa0 = wexp[p * 8 + h];
        float wb0 = wexp[p * 8 + 4 + h];
        acc0 += wa0 * us2f(ftb[(size_t)s0 * 512 + t]);
        acc1 += wb0 * us2f(ftb[(size_t)s0 * 512 + 256 + t]);
        ws0 += wa0;
        ws1 += wb0;
    }
    float bgv = ld(bg, t, isbf);
    float v0 = (end > beg) ? (acc0 / ws0) : 0.f;
    float v1 = (end > beg) ? (acc1 / ws1) : 0.f;
    v0 += bgv; v1 += bgv;
    __shared__ float red[512];
    red[t] = v0;
    red[256 + t] = v1;
    __syncthreads();
    if (t < 64) {
        float m0 = 0.25f * (red[t] + red[t + 64] + red[t + 128] + red[t + 192]);
        float m1 = 0.25f * (red[256 + t] + red[320 + t] + red[384 + t] + red[448 + t]);
        aggm[(size_t)(n * 2 + 0) * HID + t] = m0;
        aggm[(size_t)(n * 2 + 1) * HID + t] = m1;
    }
}

// x = elu( aggm + x @ W_res + b_res )   (in-place, row-local)
__global__ __launch_bounds__(256) void k_update(float* __restrict__ x,
                                                const float* __restrict__ aggm,
                                                const void* __restrict__ Wr,
                                                const void* __restrict__ br,
                                                const int* __restrict__ flag) {
    const int isbf = flag[0];
    __shared__ float sW[HID * HID];  // 16 KB
    __shared__ float sX[4][HID];
    __shared__ float sB[HID];
    int t = threadIdx.x;
    for (int i = t; i < HID * HID; i += 256) sW[i] = ld(Wr, i, isbf);
    if (t < HID) sB[t] = ld(br, t, isbf);
    int row0 = blockIdx.x * 4;
    int rr = t >> 6, col = t & 63;
    int row = row0 + rr;
    sX[rr][col] = (row < ROWS) ? x[(size_t)row * HID + col] : 0.f;
    __syncthreads();
    if (row >= ROWS) return;
    float acc = sB[col] + aggm[(size_t)row * HID + col];
#pragma unroll
    for (int k = 0; k < HID; k++) acc += sX[rr][k] * sW[k * HID + col];
    x[(size_t)row * HID + col] = acc > 0.f ? acc : expm1f(acc);
}

// out[b][n][o] = x[row=n*2+b] @ W_dec + b_dec ; output dtype follows input dtype
__global__ __launch_bounds__(256) void k_dec(const float* __restrict__ x,
                                             const void* __restrict__ Wd,
                                             const void* __restrict__ bd,
                                             void* __restrict__ out,
                                             const int* __restrict__ flag) {
    const int isbf = flag[0];
    __shared__ float sW[HID * OUT_DIM];
    __shared__ float sB[OUT_DIM];
    int t = threadIdx.x;
    for (int i = t; i < HID * OUT_DIM; i += 256) sW[i] = ld(Wd, i, isbf);
    if (t < OUT_DIM) sB[t] = ld(bd, t, isbf);
    __syncthreads();
    int gid = blockIdx.x * 256 + t;
    if (gid >= ROWS * OUT_DIM) return;
    int row = gid >> 3, o = gid & 7;
    int n = row >> 1, b = row & 1;
    float acc = sB[o];
#pragma unroll
    for (int k = 0; k < HID; k++) acc += x[(size_t)row * HID + k] * sW[k * OUT_DIM + o];
    size_t oi = (size_t)(b * N_NODES + n) * OUT_DIM + o;
    if (isbf) ((unsigned short*)out)[oi] = f2us(acc);
    else      ((float*)out)[oi] = acc;
}

extern "C" void kernel_launch(void* const* d_in, const int* in_sizes, int n_in,
                              void* d_out, int out_size, void* d_ws, size_t ws_size,
                              hipStream_t stream) {
    const void* h     = d_in[0];
    const int*  ei    = (const int*)d_in[1];
    const void* W_enc = d_in[2];
    const void* b_enc = d_in[3];
    const void* W_gat = d_in[4];
    const void* a_l   = d_in[5];
    const void* a_r   = d_in[6];
    const void* b_gat = d_in[7];
    const void* W_res = d_in[8];
    const void* b_res = d_in[9];
    const void* W_dec = d_in[10];
    const void* b_dec = d_in[11];

    float* ws = (float*)d_ws;
    int*   flag     = (int*)(ws + WS_FLAG);
    float* x        = ws + WS_X;
    unsigned short* ftb = (unsigned short*)(ws + WS_FT);
    float* el       = ws + WS_EL;
    float* er       = ws + WS_ER;
    float* aggm     = ws + WS_AGGM;
    int*   deg      = (int*)(ws + WS_DEG);
    int*   rowstart = (int*)(ws + WS_ROWSTART);
    int*   cursor   = (int*)(ws + WS_CUR);
    int*   csrc     = (int*)(ws + WS_CSRC);
    int*   cdst     = (int*)(ws + WS_CDST);
    float* wexp     = ws + WS_WEXP;

    const int* src = ei;
    const int* dst = ei + N_EDGES;

    k_sniff<<<1, 256, 0, stream>>>(h, flag);
    k_enc<<<ROWS / 4, 256, 0, stream>>>(h, W_enc, b_enc, x, flag);

    hipMemsetAsync(deg, 0, N_NODES * sizeof(int), stream);
    k_hist<<<(N_EDGES + 255) / 256, 256, 0, stream>>>(dst, deg);
    k_scan<<<1, 1024, 0, stream>>>(deg, rowstart, cursor);
    k_scatter<<<(N_EDGES + 255) / 256, 256, 0, stream>>>(src, dst, cursor, csrc, cdst);

    for (int r = 0; r < 2; r++) {
        k_gat_proj<<<ROWS / 8, 256, 0, stream>>>(x, W_gat, a_l, a_r, ftb, el, er, flag);
        k_wexp<<<(N_EDGES + 255) / 256, 256, 0, stream>>>(csrc, cdst, el, er, wexp);
        k_agg<<<N_NODES, 256, 0, stream>>>(rowstart, csrc, wexp, ftb, b_gat, aggm, flag);
        k_update<<<ROWS / 4, 256, 0, stream>>>(x, aggm, W_res, b_res, flag);
    }
    k_dec<<<(ROWS * OUT_DIM + 255) / 256, 256, 0, stream>>>(x, W_dec, b_dec, d_out, flag);
}

// Round 6
// 453.457 us; speedup vs baseline: 11.0087x; 1.3063x over previous
//
#include <hip/hip_runtime.h>
#include <hip/hip_bf16.h>

#define N_NODES 20000
#define N_EDGES 320000
#define BATCH 2
#define IN_DIM 32
#define HID 64
#define HEADS 4
#define OUT_DIM 8
#define ROWS (N_NODES * BATCH) /* 40000 */
#define SLOPE 0.2f

typedef __hip_bfloat16 bf16;
typedef short v8s __attribute__((ext_vector_type(8)));
typedef float v4f __attribute__((ext_vector_type(4)));

// ---- workspace layout (float slots) ----
#define WS_FLAG 0
#define WS_X        64        /* 2,560,000 floats */
#define WS_FT       2560064   /* 10,240,000 bf16 = 5,120,000 float slots */
#define WS_EL       7680064   /* 160,000 */
#define WS_ER       7840064   /* 160,000 */
#define WS_AGGM     8000064   /* 2,560,000 */
#define WS_DEG      10560064  /* 20,032 ints */
#define WS_ROWSTART 10580096  /* 20,032 ints (20001 used) */
#define WS_CUR      10600128  /* 20,032 ints */
#define WS_CSRC     10620160  /* 320,000 ints */
#define WS_CDST     10940160  /* 320,000 ints */
#define WS_WEXP     11260160  /* 2,560,000 floats */
#define WS_END      13820160  /* 55.3 MB */

__device__ __forceinline__ float us2f(unsigned short u) {
    union { unsigned int i; float f; } z; z.i = ((unsigned int)u) << 16; return z.f;
}
__device__ __forceinline__ unsigned short f2us(float f) {
    bf16 b = __float2bfloat16(f);
    return *(unsigned short*)&b;
}
__device__ __forceinline__ float ld(const void* p, int i, int isbf) {
    if (isbf) return us2f(((const unsigned short*)p)[i]);
    return ((const float*)p)[i];
}
__device__ __forceinline__ float lrexp(float v) {
    v = v > 0.f ? v : SLOPE * v;
    return __expf(fminf(v, 60.f));
}

// bf16-vs-fp32 input sniffer (see R2 notes).
__global__ __launch_bounds__(256) void k_sniff(const void* __restrict__ h, int* __restrict__ flag) {
    __shared__ int cnt;
    if (threadIdx.x == 0) cnt = 0;
    __syncthreads();
    const unsigned short* u = (const unsigned short*)h;
    unsigned short v = u[2 * threadIdx.x];
    int ef = (v >> 7) & 0xFF;
    if (ef >= 100 && ef <= 150) atomicAdd(&cnt, 1);
    __syncthreads();
    if (threadIdx.x == 0) flag[0] = (cnt >= 192) ? 1 : 0;
}

// ---- CSR build ----
__global__ __launch_bounds__(256) void k_hist(const int* __restrict__ dst, int* __restrict__ deg) {
    int e = blockIdx.x * 256 + threadIdx.x;
    if (e < N_EDGES) atomicAdd(&deg[dst[e]], 1);
}

__global__ __launch_bounds__(1024) void k_scan(const int* __restrict__ deg,
                                               int* __restrict__ rowstart,
                                               int* __restrict__ cursor) {
    __shared__ int ssum[1024];
    int t = threadIdx.x;
    int base = t * 20;
    int local[20];
    int s = 0;
#pragma unroll
    for (int i = 0; i < 20; i++) {
        int v = (base + i < N_NODES) ? deg[base + i] : 0;
        local[i] = s;
        s += v;
    }
    ssum[t] = s;
    __syncthreads();
    for (int off = 1; off < 1024; off <<= 1) {
        int v = (t >= off) ? ssum[t - off] : 0;
        __syncthreads();
        if (t >= off) ssum[t] += v;
        __syncthreads();
    }
    int prev = (t == 0) ? 0 : ssum[t - 1];
#pragma unroll
    for (int i = 0; i < 20; i++) {
        if (base + i < N_NODES) {
            int v = prev + local[i];
            rowstart[base + i] = v;
            cursor[base + i] = v;
        }
    }
    if (t == 1023) rowstart[N_NODES] = ssum[1023];
}

__global__ __launch_bounds__(256) void k_scatter(const int* __restrict__ src,
                                                 const int* __restrict__ dst,
                                                 int* __restrict__ cursor,
                                                 int* __restrict__ csrc,
                                                 int* __restrict__ cdst) {
    int e = blockIdx.x * 256 + threadIdx.x;
    if (e >= N_EDGES) return;
    int d = dst[e];
    int pos = atomicAdd(&cursor[d], 1);
    csrc[pos] = src[e];
    cdst[pos] = d;
}

// x[row=n*2+b][0..63] = h[b][n][:] @ W_enc + b_enc
__global__ __launch_bounds__(256) void k_enc(const void* __restrict__ h,
                                             const void* __restrict__ W,
                                             const void* __restrict__ bias,
                                             float* __restrict__ x,
                                             const int* __restrict__ flag) {
    const int isbf = flag[0];
    __shared__ float sW[IN_DIM * HID];
    __shared__ float sB[HID];
    int t = threadIdx.x;
    for (int i = t; i < IN_DIM * HID; i += 256) sW[i] = ld(W, i, isbf);
    if (t < HID) sB[t] = ld(bias, t, isbf);
    __syncthreads();
    int row = blockIdx.x * 4 + (t >> 6);
    int col = t & 63;
    if (row >= ROWS) return;
    int n = row >> 1, b = row & 1;
    size_t hbase = (size_t)(b * N_NODES + n) * IN_DIM;
    float acc = sB[col];
#pragma unroll
    for (int k = 0; k < IN_DIM; k++) acc += ld(h, hbase + k, isbf) * sW[k * HID + col];
    x[(size_t)row * HID + col] = acc;
}

// MFMA version: ft[row][0..255] = x[row] @ Wg (bf16 inputs, fp32 acc).
// Block = 64 rows; wave w = head w (cols w*64..+63). 16x16x32 bf16 MFMA.
// A layout: A[m=lane&15][k=quad*8+j]; B: B[k=quad*8+j][n=lane&15];
// C/D: col=lane&15, row=quad*4+reg.
__global__ __launch_bounds__(256) void k_gat_proj(const float* __restrict__ x,
                                                  const void* __restrict__ Wg,
                                                  const void* __restrict__ al,
                                                  const void* __restrict__ ar,
                                                  unsigned short* __restrict__ ftb,
                                                  float* __restrict__ el,
                                                  float* __restrict__ er,
                                                  const int* __restrict__ flag) {
    const int isbf = flag[0];
    __shared__ unsigned short sFt[64 * 256];   // 32 KB, ft tile for coalesced store
    int t = threadIdx.x;
    int w = t >> 6;          // wave == head
    int lane = t & 63;
    int quad = lane >> 4;
    int m16 = lane & 15;
    int row0 = blockIdx.x * 64;

    // B fragments: Bf[ct][ks] covers Wg[ks*32 + quad*8 .. +8][w*64 + ct*16 + m16]
    v8s Bf[4][2];
    float alv[4], arv[4];
#pragma unroll
    for (int ct = 0; ct < 4; ct++) {
        int gcol = w * 64 + ct * 16 + m16;
        alv[ct] = ld(al, gcol, isbf);
        arv[ct] = ld(ar, gcol, isbf);
#pragma unroll
        for (int ks = 0; ks < 2; ks++) {
#pragma unroll
            for (int j = 0; j < 8; j++) {
                int k = ks * 32 + quad * 8 + j;
                Bf[ct][ks][j] = (short)(isbf ? ((const unsigned short*)Wg)[k * 256 + gcol]
                                             : f2us(((const float*)Wg)[k * 256 + gcol]));
            }
        }
    }

    v4f acc[4][4];
#pragma unroll
    for (int rt = 0; rt < 4; rt++)
#pragma unroll
        for (int ct = 0; ct < 4; ct++)
            acc[rt][ct] = (v4f)(0.f);

#pragma unroll
    for (int ks = 0; ks < 2; ks++) {
#pragma unroll
        for (int rt = 0; rt < 4; rt++) {
            int grow = row0 + rt * 16 + m16;
            const float4* xp = (const float4*)(x + (size_t)grow * 64 + ks * 32 + quad * 8);
            float4 xa = xp[0], xb = xp[1];
            v8s Af;
            Af[0] = (short)f2us(xa.x); Af[1] = (short)f2us(xa.y);
            Af[2] = (short)f2us(xa.z); Af[3] = (short)f2us(xa.w);
            Af[4] = (short)f2us(xb.x); Af[5] = (short)f2us(xb.y);
            Af[6] = (short)f2us(xb.z); Af[7] = (short)f2us(xb.w);
#pragma unroll
            for (int ct = 0; ct < 4; ct++)
                acc[rt][ct] = __builtin_amdgcn_mfma_f32_16x16x32_bf16(Af, Bf[ct][ks], acc[rt][ct], 0, 0, 0);
        }
    }

    // el/er from C-frags: per row, dot over this wave's 64 cols with a_l/a_r.
#pragma unroll
    for (int rt = 0; rt < 4; rt++) {
#pragma unroll
        for (int r = 0; r < 4; r++) {
            float cl = 0.f, cr = 0.f;
#pragma unroll
            for (int ct = 0; ct < 4; ct++) {
                float v = acc[rt][ct][r];
                cl += v * alv[ct];
                cr += v * arv[ct];
            }
            cl += __shfl_xor(cl, 1); cr += __shfl_xor(cr, 1);
            cl += __shfl_xor(cl, 2); cr += __shfl_xor(cr, 2);
            cl += __shfl_xor(cl, 4); cr += __shfl_xor(cr, 4);
            cl += __shfl_xor(cl, 8); cr += __shfl_xor(cr, 8);
            if (m16 == 0) {
                int grow = row0 + rt * 16 + quad * 4 + r;
                el[grow * 4 + w] = cl;
                er[grow * 4 + w] = cr;
            }
        }
    }

    // ft tile -> LDS (bf16) -> coalesced global store
#pragma unroll
    for (int rt = 0; rt < 4; rt++)
#pragma unroll
        for (int ct = 0; ct < 4; ct++)
#pragma unroll
            for (int r = 0; r < 4; r++)
                sFt[(rt * 16 + quad * 4 + r) * 256 + w * 64 + ct * 16 + m16] = f2us(acc[rt][ct][r]);
    __syncthreads();
    const unsigned int* sFt32 = (const unsigned int*)sFt;
    unsigned int* ftb32 = (unsigned int*)ftb;
    int c = t & 127;
#pragma unroll
    for (int r2 = 0; r2 < 32; r2++) {
        int rloc = r2 * 2 + (t >> 7);
        ftb32[(size_t)(row0 + rloc) * 128 + c] = sFt32[rloc * 128 + c];
    }
}

// per CSR position: wexp[p][i] = exp(leakyrelu(el[src][i] + er[dst][i])), i = b*4+h
__global__ __launch_bounds__(256) void k_wexp(const int* __restrict__ csrc,
                                              const int* __restrict__ cdst,
                                              const float* __restrict__ el,
                                              const float* __restrict__ er,
                                              float* __restrict__ wexp) {
    int p = blockIdx.x * 256 + threadIdx.x;
    if (p >= N_EDGES) return;
    int s = csrc[p], d = cdst[p];
    float4 ea = ((const float4*)el)[s * 2];
    float4 eb = ((const float4*)el)[s * 2 + 1];
    float4 ra = ((const float4*)er)[d * 2];
    float4 rb = ((const float4*)er)[d * 2 + 1];
    float4 wa, wb;
    wa.x = lrexp(ea.x + ra.x); wa.y = lrexp(ea.y + ra.y);
    wa.z = lrexp(ea.z + ra.z); wa.w = lrexp(ea.w + ra.w);
    wb.x = lrexp(eb.x + rb.x); wb.y = lrexp(eb.y + rb.y);
    wb.z = lrexp(eb.z + rb.z); wb.w = lrexp(eb.w + rb.w);
    ((float4*)wexp)[p * 2] = wa;
    ((float4*)wexp)[p * 2 + 1] = wb;
}

// One block per dst node, both batches.
__global__ __launch_bounds__(256) void k_agg(const int* __restrict__ rowstart,
                                             const int* __restrict__ csrc,
                                             const float* __restrict__ wexp,
                                             const unsigned short* __restrict__ ftb,
                                             const void* __restrict__ bg,
                                             float* __restrict__ aggm,
                                             const int* __restrict__ flag) {
    const int isbf = flag[0];
    int n = blockIdx.x;
    int t = threadIdx.x;
    int h = t >> 6;
    int beg = rowstart[n], end = rowstart[n + 1];
    float acc0 = 0.f, acc1 = 0.f, ws0 = 0.f, ws1 = 0.f;
    int p = beg;
    for (; p + 1 < end; p += 2) {
        int s0 = csrc[p], s1 = csrc[p + 1];
        float wa0 = wexp[p * 8 + h];
        float wb0 = wexp[p * 8 + 4 + h];
        float wa1 = wexp[(p + 1) * 8 + h];
        float wb1 = wexp[(p + 1) * 8 + 4 + h];
        unsigned short q0a = ftb[(size_t)s0 * 512 + t];
        unsigned short q0b = ftb[(size_t)s0 * 512 + 256 + t];
        unsigned short q1a = ftb[(size_t)s1 * 512 + t];
        unsigned short q1b = ftb[(size_t)s1 * 512 + 256 + t];
        acc0 += wa0 * us2f(q0a) + wa1 * us2f(q1a);
        acc1 += wb0 * us2f(q0b) + wb1 * us2f(q1b);
        ws0 += wa0 + wa1;
        ws1 += wb0 + wb1;
    }
    if (p < end) {
        int s0 = csrc[p];
        float wa0 = wexp[p * 8 + h];
        float wb0 = wexp[p * 8 + 4 + h];
        acc0 += wa0 * us2f(ftb[(size_t)s0 * 512 + t]);
        acc1 += wb0 * us2f(ftb[(size_t)s0 * 512 + 256 + t]);
        ws0 += wa0;
        ws1 += wb0;
    }
    float bgv = ld(bg, t, isbf);
    float v0 = (end > beg) ? (acc0 / ws0) : 0.f;
    float v1 = (end > beg) ? (acc1 / ws1) : 0.f;
    v0 += bgv; v1 += bgv;
    __shared__ float red[512];
    red[t] = v0;
    red[256 + t] = v1;
    __syncthreads();
    if (t < 64) {
        float m0 = 0.25f * (red[t] + red[t + 64] + red[t + 128] + red[t + 192]);
        float m1 = 0.25f * (red[256 + t] + red[320 + t] + red[384 + t] + red[448 + t]);
        aggm[(size_t)(n * 2 + 0) * HID + t] = m0;
        aggm[(size_t)(n * 2 + 1) * HID + t] = m1;
    }
}

// x = elu( aggm + x @ W_res + b_res )   (in-place, row-local)
__global__ __launch_bounds__(256) void k_update(float* __restrict__ x,
                                                const float* __restrict__ aggm,
                                                const void* __restrict__ Wr,
                                                const void* __restrict__ br,
                                                const int* __restrict__ flag) {
    const int isbf = flag[0];
    __shared__ float sW[HID * HID];  // 16 KB
    __shared__ float sX[4][HID];
    __shared__ float sB[HID];
    int t = threadIdx.x;
    for (int i = t; i < HID * HID; i += 256) sW[i] = ld(Wr, i, isbf);
    if (t < HID) sB[t] = ld(br, t, isbf);
    int row0 = blockIdx.x * 4;
    int rr = t >> 6, col = t & 63;
    int row = row0 + rr;
    sX[rr][col] = (row < ROWS) ? x[(size_t)row * HID + col] : 0.f;
    __syncthreads();
    if (row >= ROWS) return;
    float acc = sB[col] + aggm[(size_t)row * HID + col];
#pragma unroll
    for (int k = 0; k < HID; k++) acc += sX[rr][k] * sW[k * HID + col];
    x[(size_t)row * HID + col] = acc > 0.f ? acc : expm1f(acc);
}

// out[b][n][o] = x[row=n*2+b] @ W_dec + b_dec ; output dtype follows input dtype
__global__ __launch_bounds__(256) void k_dec(const float* __restrict__ x,
                                             const void* __restrict__ Wd,
                                             const void* __restrict__ bd,
                                             void* __restrict__ out,
                                             const int* __restrict__ flag) {
    const int isbf = flag[0];
    __shared__ float sW[HID * OUT_DIM];
    __shared__ float sB[OUT_DIM];
    int t = threadIdx.x;
    for (int i = t; i < HID * OUT_DIM; i += 256) sW[i] = ld(Wd, i, isbf);
    if (t < OUT_DIM) sB[t] = ld(bd, t, isbf);
    __syncthreads();
    int gid = blockIdx.x * 256 + t;
    if (gid >= ROWS * OUT_DIM) return;
    int row = gid >> 3, o = gid & 7;
    int n = row >> 1, b = row & 1;
    float acc = sB[o];
#pragma unroll
    for (int k = 0; k < HID; k++) acc += x[(size_t)row * HID + k] * sW[k * OUT_DIM + o];
    size_t oi = (size_t)(b * N_NODES + n) * OUT_DIM + o;
    if (isbf) ((unsigned short*)out)[oi] = f2us(acc);
    else      ((float*)out)[oi] = acc;
}

extern "C" void kernel_launch(void* const* d_in, const int* in_sizes, int n_in,
                              void* d_out, int out_size, void* d_ws, size_t ws_size,
                              hipStream_t stream) {
    const void* h     = d_in[0];
    const int*  ei    = (const int*)d_in[1];
    const void* W_enc = d_in[2];
    const void* b_enc = d_in[3];
    const void* W_gat = d_in[4];
    const void* a_l   = d_in[5];
    const void* a_r   = d_in[6];
    const void* b_gat = d_in[7];
    const void* W_res = d_in[8];
    const void* b_res = d_in[9];
    const void* W_dec = d_in[10];
    const void* b_dec = d_in[11];

    float* ws = (float*)d_ws;
    int*   flag     = (int*)(ws + WS_FLAG);
    float* x        = ws + WS_X;
    unsigned short* ftb = (unsigned short*)(ws + WS_FT);
    float* el       = ws + WS_EL;
    float* er       = ws + WS_ER;
    float* aggm     = ws + WS_AGGM;
    int*   deg      = (int*)(ws + WS_DEG);
    int*   rowstart = (int*)(ws + WS_ROWSTART);
    int*   cursor   = (int*)(ws + WS_CUR);
    int*   csrc     = (int*)(ws + WS_CSRC);
    int*   cdst     = (int*)(ws + WS_CDST);
    float* wexp     = ws + WS_WEXP;

    const int* src = ei;
    const int* dst = ei + N_EDGES;

    k_sniff<<<1, 256, 0, stream>>>(h, flag);
    k_enc<<<ROWS / 4, 256, 0, stream>>>(h, W_enc, b_enc, x, flag);

    hipMemsetAsync(deg, 0, N_NODES * sizeof(int), stream);
    k_hist<<<(N_EDGES + 255) / 256, 256, 0, stream>>>(dst, deg);
    k_scan<<<1, 1024, 0, stream>>>(deg, rowstart, cursor);
    k_scatter<<<(N_EDGES + 255) / 256, 256, 0, stream>>>(src, dst, cursor, csrc, cdst);

    for (int r = 0; r < 2; r++) {
        k_gat_proj<<<ROWS / 64, 256, 0, stream>>>(x, W_gat, a_l, a_r, ftb, el, er, flag);
        k_wexp<<<(N_EDGES + 255) / 256, 256, 0, stream>>>(csrc, cdst, el, er, wexp);
        k_agg<<<N_NODES, 256, 0, stream>>>(rowstart, csrc, wexp, ftb, b_gat, aggm, flag);
        k_update<<<ROWS / 4, 256, 0, stream>>>(x, aggm, W_res, b_res, flag);
    }
    k_dec<<<(ROWS * OUT_DIM + 255) / 256, 256, 0, stream>>>(x, W_dec, b_dec, d_out, flag);
}

// Round 7
// 395.029 us; speedup vs baseline: 12.6370x; 1.1479x over previous
//
#include <hip/hip_runtime.h>
#include <hip/hip_bf16.h>

#define N_NODES 20000
#define N_EDGES 320000
#define BATCH 2
#define IN_DIM 32
#define HID 64
#define HEADS 4
#define OUT_DIM 8
#define ROWS (N_NODES * BATCH) /* 40000 */
#define SLOPE 0.2f

typedef __hip_bfloat16 bf16;
typedef short v8s __attribute__((ext_vector_type(8)));
typedef float v4f __attribute__((ext_vector_type(4)));

// ---- workspace layout (float slots) ----
#define WS_FLAG 0
#define WS_X        64        /* 2,560,000 floats */
#define WS_FT       2560064   /* ftb32: 20000*256 u32 = 5,120,000 slots */
#define WS_EL       7680064   /* 160,000 */
#define WS_ER       7840064   /* 160,000 */
#define WS_AGGM     8000064   /* 2,560,000 */
#define WS_DEG      10560064  /* 20,032 ints */
#define WS_ROWSTART 10580096  /* 20,032 ints (20001 used) */
#define WS_CUR      10600128  /* 20,032 ints */
#define WS_CSRC     10620160  /* 320,000 ints */
#define WS_END      10940160  /* 43.8 MB */

__device__ __forceinline__ float us2f(unsigned short u) {
    union { unsigned int i; float f; } z; z.i = ((unsigned int)u) << 16; return z.f;
}
__device__ __forceinline__ float u2f_lo(unsigned int u) {
    union { unsigned int i; float f; } z; z.i = u << 16; return z.f;
}
__device__ __forceinline__ float u2f_hi(unsigned int u) {
    union { unsigned int i; float f; } z; z.i = u & 0xffff0000u; return z.f;
}
__device__ __forceinline__ unsigned short f2us(float f) {
    bf16 b = __float2bfloat16(f);
    return *(unsigned short*)&b;
}
__device__ __forceinline__ float ld(const void* p, int i, int isbf) {
    if (isbf) return us2f(((const unsigned short*)p)[i]);
    return ((const float*)p)[i];
}
__device__ __forceinline__ float lrexp(float v) {
    v = v > 0.f ? v : SLOPE * v;
    return __expf(fminf(v, 60.f));
}

// bf16-vs-fp32 input sniffer (see R2 notes).
__global__ __launch_bounds__(256) void k_sniff(const void* __restrict__ h, int* __restrict__ flag) {
    __shared__ int cnt;
    if (threadIdx.x == 0) cnt = 0;
    __syncthreads();
    const unsigned short* u = (const unsigned short*)h;
    unsigned short v = u[2 * threadIdx.x];
    int ef = (v >> 7) & 0xFF;
    if (ef >= 100 && ef <= 150) atomicAdd(&cnt, 1);
    __syncthreads();
    if (threadIdx.x == 0) flag[0] = (cnt >= 192) ? 1 : 0;
}

// ---- CSR build ----
__global__ __launch_bounds__(256) void k_hist(const int* __restrict__ dst, int* __restrict__ deg) {
    int e = blockIdx.x * 256 + threadIdx.x;
    if (e < N_EDGES) atomicAdd(&deg[dst[e]], 1);
}

__global__ __launch_bounds__(1024) void k_scan(const int* __restrict__ deg,
                                               int* __restrict__ rowstart,
                                               int* __restrict__ cursor) {
    __shared__ int ssum[1024];
    int t = threadIdx.x;
    int base = t * 20;
    int local[20];
    int s = 0;
#pragma unroll
    for (int i = 0; i < 20; i++) {
        int v = (base + i < N_NODES) ? deg[base + i] : 0;
        local[i] = s;
        s += v;
    }
    ssum[t] = s;
    __syncthreads();
    for (int off = 1; off < 1024; off <<= 1) {
        int v = (t >= off) ? ssum[t - off] : 0;
        __syncthreads();
        if (t >= off) ssum[t] += v;
        __syncthreads();
    }
    int prev = (t == 0) ? 0 : ssum[t - 1];
#pragma unroll
    for (int i = 0; i < 20; i++) {
        if (base + i < N_NODES) {
            int v = prev + local[i];
            rowstart[base + i] = v;
            cursor[base + i] = v;
        }
    }
    if (t == 1023) rowstart[N_NODES] = ssum[1023];
}

__global__ __launch_bounds__(256) void k_scatter(const int* __restrict__ src,
                                                 const int* __restrict__ dst,
                                                 int* __restrict__ cursor,
                                                 int* __restrict__ csrc) {
    int e = blockIdx.x * 256 + threadIdx.x;
    if (e >= N_EDGES) return;
    int pos = atomicAdd(&cursor[dst[e]], 1);
    csrc[pos] = src[e];
}

// x[row=n*2+b][0..63] = h[b][n][:] @ W_enc + b_enc
__global__ __launch_bounds__(256) void k_enc(const void* __restrict__ h,
                                             const void* __restrict__ W,
                                             const void* __restrict__ bias,
                                             float* __restrict__ x,
                                             const int* __restrict__ flag) {
    const int isbf = flag[0];
    __shared__ float sW[IN_DIM * HID];
    __shared__ float sB[HID];
    int t = threadIdx.x;
    for (int i = t; i < IN_DIM * HID; i += 256) sW[i] = ld(W, i, isbf);
    if (t < HID) sB[t] = ld(bias, t, isbf);
    __syncthreads();
    int row = blockIdx.x * 4 + (t >> 6);
    int col = t & 63;
    if (row >= ROWS) return;
    int n = row >> 1, b = row & 1;
    size_t hbase = (size_t)(b * N_NODES + n) * IN_DIM;
    float acc = sB[col];
#pragma unroll
    for (int k = 0; k < IN_DIM; k++) acc += ld(h, hbase + k, isbf) * sW[k * HID + col];
    x[(size_t)row * HID + col] = acc;
}

// MFMA gat_proj. Block = 64 rows (= 32 nodes x 2 batches); wave w = head w.
// ftb32[s*256 + col] packs (bf16 ft[s,b=0,col], bf16 ft[s,b=1,col]) in one u32.
// C-frag regs r=0,1 are rows (2s, 2s+1) -> direct packed store, no LDS.
__global__ __launch_bounds__(256) void k_gat_proj(const float* __restrict__ x,
                                                  const void* __restrict__ Wg,
                                                  const void* __restrict__ al,
                                                  const void* __restrict__ ar,
                                                  unsigned int* __restrict__ ftb32,
                                                  float* __restrict__ el,
                                                  float* __restrict__ er,
                                                  const int* __restrict__ flag) {
    const int isbf = flag[0];
    int t = threadIdx.x;
    int w = t >> 6;          // wave == head
    int lane = t & 63;
    int quad = lane >> 4;
    int m16 = lane & 15;
    int row0 = blockIdx.x * 64;

    v8s Bf[4][2];
    float alv[4], arv[4];
#pragma unroll
    for (int ct = 0; ct < 4; ct++) {
        int gcol = w * 64 + ct * 16 + m16;
        alv[ct] = ld(al, gcol, isbf);
        arv[ct] = ld(ar, gcol, isbf);
#pragma unroll
        for (int ks = 0; ks < 2; ks++) {
#pragma unroll
            for (int j = 0; j < 8; j++) {
                int k = ks * 32 + quad * 8 + j;
                Bf[ct][ks][j] = (short)(isbf ? ((const unsigned short*)Wg)[k * 256 + gcol]
                                             : f2us(((const float*)Wg)[k * 256 + gcol]));
            }
        }
    }

    v4f acc[4][4];
#pragma unroll
    for (int rt = 0; rt < 4; rt++)
#pragma unroll
        for (int ct = 0; ct < 4; ct++)
            acc[rt][ct] = (v4f)(0.f);

#pragma unroll
    for (int ks = 0; ks < 2; ks++) {
#pragma unroll
        for (int rt = 0; rt < 4; rt++) {
            int grow = row0 + rt * 16 + m16;
            const float4* xp = (const float4*)(x + (size_t)grow * 64 + ks * 32 + quad * 8);
            float4 xa = xp[0], xb = xp[1];
            v8s Af;
            Af[0] = (short)f2us(xa.x); Af[1] = (short)f2us(xa.y);
            Af[2] = (short)f2us(xa.z); Af[3] = (short)f2us(xa.w);
            Af[4] = (short)f2us(xb.x); Af[5] = (short)f2us(xb.y);
            Af[6] = (short)f2us(xb.z); Af[7] = (short)f2us(xb.w);
#pragma unroll
            for (int ct = 0; ct < 4; ct++)
                acc[rt][ct] = __builtin_amdgcn_mfma_f32_16x16x32_bf16(Af, Bf[ct][ks], acc[rt][ct], 0, 0, 0);
        }
    }

    // el/er: per row, dot over this wave's 64 cols with a_l/a_r; butterfly over low 4 bits.
#pragma unroll
    for (int rt = 0; rt < 4; rt++) {
#pragma unroll
        for (int r = 0; r < 4; r++) {
            float cl = 0.f, cr = 0.f;
#pragma unroll
            for (int ct = 0; ct < 4; ct++) {
                float v = acc[rt][ct][r];
                cl += v * alv[ct];
                cr += v * arv[ct];
            }
            cl += __shfl_xor(cl, 1); cr += __shfl_xor(cr, 1);
            cl += __shfl_xor(cl, 2); cr += __shfl_xor(cr, 2);
            cl += __shfl_xor(cl, 4); cr += __shfl_xor(cr, 4);
            cl += __shfl_xor(cl, 8); cr += __shfl_xor(cr, 8);
            if (m16 == 0) {
                int grow = row0 + rt * 16 + quad * 4 + r;
                el[grow * 4 + w] = cl;
                er[grow * 4 + w] = cr;
            }
        }
    }

    // packed batch-pair stores straight from C-frags
#pragma unroll
    for (int rt = 0; rt < 4; rt++) {
        int sbase = (row0 + rt * 16 + quad * 4) >> 1;   // node for regs r=0,1
#pragma unroll
        for (int ct = 0; ct < 4; ct++) {
            int gcol = w * 64 + ct * 16 + m16;
            unsigned int u01 = (unsigned int)f2us(acc[rt][ct][0]) | ((unsigned int)f2us(acc[rt][ct][1]) << 16);
            unsigned int u23 = (unsigned int)f2us(acc[rt][ct][2]) | ((unsigned int)f2us(acc[rt][ct][3]) << 16);
            ftb32[(size_t)sbase * 256 + gcol] = u01;
            ftb32[(size_t)(sbase + 1) * 256 + gcol] = u23;
        }
    }
}

// One block per dst node, both batches. Chunked LDS staging of csrc + inline exp-weights.
__global__ __launch_bounds__(256) void k_agg(const int* __restrict__ rowstart,
                                             const int* __restrict__ csrc,
                                             const float* __restrict__ el,
                                             const float* __restrict__ er,
                                             const unsigned int* __restrict__ ftb32,
                                             const void* __restrict__ bg,
                                             float* __restrict__ aggm,
                                             const int* __restrict__ flag) {
    const int isbf = flag[0];
    int n = blockIdx.x;
    int t = threadIdx.x;
    int h = t >> 6;
    int beg = rowstart[n], end = rowstart[n + 1];
    __shared__ int sC[64];
    __shared__ float2 sWe[256];
    __shared__ float red[512];
    float acc0 = 0.f, acc1 = 0.f, ws0 = 0.f, ws1 = 0.f;
    for (int p0 = beg; p0 < end; p0 += 64) {
        int cnt = min(64, end - p0);
        __syncthreads();
        if (t < cnt * 4) {
            int e = t >> 2, hh = t & 3;
            int s = csrc[p0 + e];
            if (hh == 0) sC[e] = s;
            float e0 = el[s * 8 + hh];
            float e1 = el[s * 8 + 4 + hh];
            float r0 = er[n * 8 + hh];
            float r1 = er[n * 8 + 4 + hh];
            sWe[t] = make_float2(lrexp(e0 + r0), lrexp(e1 + r1));
        }
        __syncthreads();
#pragma unroll 4
        for (int e = 0; e < cnt; e++) {
            int s = sC[e];
            float2 we = sWe[e * 4 + h];
            unsigned int q = ftb32[(size_t)s * 256 + t];
            acc0 += we.x * u2f_lo(q);
            ws0 += we.x;
            acc1 += we.y * u2f_hi(q);
            ws1 += we.y;
        }
    }
    float bgv = ld(bg, t, isbf);
    float v0 = (end > beg) ? (acc0 / ws0) : 0.f;
    float v1 = (end > beg) ? (acc1 / ws1) : 0.f;
    v0 += bgv; v1 += bgv;
    red[t] = v0;
    red[256 + t] = v1;
    __syncthreads();
    if (t < 64) {
        float m0 = 0.25f * (red[t] + red[t + 64] + red[t + 128] + red[t + 192]);
        float m1 = 0.25f * (red[256 + t] + red[320 + t] + red[384 + t] + red[448 + t]);
        aggm[(size_t)(n * 2 + 0) * HID + t] = m0;
        aggm[(size_t)(n * 2 + 1) * HID + t] = m1;
    }
}

// MFMA update: x = elu( aggm + x @ W_res + b_res ), in-place.
// Block = 64 rows; wave w handles rows w*16..w*16+15 (disjoint bands -> no barrier).
__global__ __launch_bounds__(256) void k_update(float* __restrict__ x,
                                                const float* __restrict__ aggm,
                                                const void* __restrict__ Wr,
                                                const void* __restrict__ br,
                                                const int* __restrict__ flag) {
    const int isbf = flag[0];
    int t = threadIdx.x;
    int w = t >> 6;
    int lane = t & 63;
    int quad = lane >> 4;
    int m16 = lane & 15;
    int row0 = blockIdx.x * 64;

    v8s Bf[4][2];
#pragma unroll
    for (int ct = 0; ct < 4; ct++) {
        int col = ct * 16 + m16;
#pragma unroll
        for (int ks = 0; ks < 2; ks++) {
#pragma unroll
            for (int j = 0; j < 8; j++) {
                int k = ks * 32 + quad * 8 + j;
                Bf[ct][ks][j] = (short)(isbf ? ((const unsigned short*)Wr)[k * 64 + col]
                                             : f2us(((const float*)Wr)[k * 64 + col]));
            }
        }
    }

    v4f acc[4];
#pragma unroll
    for (int ct = 0; ct < 4; ct++) acc[ct] = (v4f)(0.f);

    int arow = row0 + w * 16 + m16;
#pragma unroll
    for (int ks = 0; ks < 2; ks++) {
        const float4* xp = (const float4*)(x + (size_t)arow * 64 + ks * 32 + quad * 8);
        float4 xa = xp[0], xb = xp[1];
        v8s Af;
        Af[0] = (short)f2us(xa.x); Af[1] = (short)f2us(xa.y);
        Af[2] = (short)f2us(xa.z); Af[3] = (short)f2us(xa.w);
        Af[4] = (short)f2us(xb.x); Af[5] = (short)f2us(xb.y);
        Af[6] = (short)f2us(xb.z); Af[7] = (short)f2us(xb.w);
#pragma unroll
        for (int ct = 0; ct < 4; ct++)
            acc[ct] = __builtin_amdgcn_mfma_f32_16x16x32_bf16(Af, Bf[ct][ks], acc[ct], 0, 0, 0);
    }

#pragma unroll
    for (int ct = 0; ct < 4; ct++) {
        int col = ct * 16 + m16;
        float bv = ld(br, col, isbf);
#pragma unroll
        for (int r = 0; r < 4; r++) {
            int row = row0 + w * 16 + quad * 4 + r;
            float v = acc[ct][r] + bv + aggm[(size_t)row * 64 + col];
            x[(size_t)row * 64 + col] = v > 0.f ? v : expm1f(v);
        }
    }
}

// out[b][n][o] = x[row=n*2+b] @ W_dec + b_dec ; output dtype follows input dtype
__global__ __launch_bounds__(256) void k_dec(const float* __restrict__ x,
                                             const void* __restrict__ Wd,
                                             const void* __restrict__ bd,
                                             void* __restrict__ out,
                                             const int* __restrict__ flag) {
    const int isbf = flag[0];
    __shared__ float sW[HID * OUT_DIM];
    __shared__ float sB[OUT_DIM];
    int t = threadIdx.x;
    for (int i = t; i < HID * OUT_DIM; i += 256) sW[i] = ld(Wd, i, isbf);
    if (t < OUT_DIM) sB[t] = ld(bd, t, isbf);
    __syncthreads();
    int gid = blockIdx.x * 256 + t;
    if (gid >= ROWS * OUT_DIM) return;
    int row = gid >> 3, o = gid & 7;
    int n = row >> 1, b = row & 1;
    float acc = sB[o];
#pragma unroll
    for (int k = 0; k < HID; k++) acc += x[(size_t)row * HID + k] * sW[k * OUT_DIM + o];
    size_t oi = (size_t)(b * N_NODES + n) * OUT_DIM + o;
    if (isbf) ((unsigned short*)out)[oi] = f2us(acc);
    else      ((float*)out)[oi] = acc;
}

extern "C" void kernel_launch(void* const* d_in, const int* in_sizes, int n_in,
                              void* d_out, int out_size, void* d_ws, size_t ws_size,
                              hipStream_t stream) {
    const void* h     = d_in[0];
    const int*  ei    = (const int*)d_in[1];
    const void* W_enc = d_in[2];
    const void* b_enc = d_in[3];
    const void* W_gat = d_in[4];
    const void* a_l   = d_in[5];
    const void* a_r   = d_in[6];
    const void* b_gat = d_in[7];
    const void* W_res = d_in[8];
    const void* b_res = d_in[9];
    const void* W_dec = d_in[10];
    const void* b_dec = d_in[11];

    float* ws = (float*)d_ws;
    int*   flag     = (int*)(ws + WS_FLAG);
    float* x        = ws + WS_X;
    unsigned int* ftb32 = (unsigned int*)(ws + WS_FT);
    float* el       = ws + WS_EL;
    float* er       = ws + WS_ER;
    float* aggm     = ws + WS_AGGM;
    int*   deg      = (int*)(ws + WS_DEG);
    int*   rowstart = (int*)(ws + WS_ROWSTART);
    int*   cursor   = (int*)(ws + WS_CUR);
    int*   csrc     = (int*)(ws + WS_CSRC);

    const int* src = ei;
    const int* dst = ei + N_EDGES;

    k_sniff<<<1, 256, 0, stream>>>(h, flag);
    k_enc<<<ROWS / 4, 256, 0, stream>>>(h, W_enc, b_enc, x, flag);

    hipMemsetAsync(deg, 0, N_NODES * sizeof(int), stream);
    k_hist<<<(N_EDGES + 255) / 256, 256, 0, stream>>>(dst, deg);
    k_scan<<<1, 1024, 0, stream>>>(deg, rowstart, cursor);
    k_scatter<<<(N_EDGES + 255) / 256, 256, 0, stream>>>(src, dst, cursor, csrc);

    for (int r = 0; r < 2; r++) {
        k_gat_proj<<<ROWS / 64, 256, 0, stream>>>(x, W_gat, a_l, a_r, ftb32, el, er, flag);
        k_agg<<<N_NODES, 256, 0, stream>>>(rowstart, csrc, el, er, ftb32, b_gat, aggm, flag);
        k_update<<<ROWS / 64, 256, 0, stream>>>(x, aggm, W_res, b_res, flag);
    }
    k_dec<<<(ROWS * OUT_DIM + 255) / 256, 256, 0, stream>>>(x, W_dec, b_dec, d_out, flag);
}

// Round 8
// 341.001 us; speedup vs baseline: 14.6392x; 1.1584x over previous
//
#include <hip/hip_runtime.h>
#include <hip/hip_bf16.h>

#define N_NODES 20000
#define N_EDGES 320000
#define BATCH 2
#define IN_DIM 32
#define HID 64
#define HEADS 4
#define OUT_DIM 8
#define ROWS (N_NODES * BATCH) /* 40000 */
#define SLOPE 0.2f

typedef __hip_bfloat16 bf16;
typedef short v8s __attribute__((ext_vector_type(8)));
typedef float v4f __attribute__((ext_vector_type(4)));

// ---- workspace layout (float slots) ----
#define WS_FLAG 0
#define WS_X        64        /* 2,560,000 floats */
#define WS_FT       2560064   /* ftb32: 20000*256 u32 */
#define WS_EL       7680064   /* 160,000 */
#define WS_ER       7840064   /* 160,000 */
#define WS_AGGM     8000064   /* 2,560,000 */
#define WS_DEG      10560064  /* 20,032 ints */
#define WS_ROWSTART 10580096  /* 20,032 ints (20001 used) */
#define WS_CUR      10600128  /* 20,032 ints */
#define WS_CSRC     10620160  /* 320,000 ints */
#define WS_WXB      10940160  /* 64*272 u16 = 8,704 u32 slots (reserve 8,960) */
#define WS_WRB      10949120  /* 64*64 u16 = 2,048 u32 slots */
#define WS_END      10951168  /* ~43.8 MB */

__device__ __forceinline__ float us2f(unsigned short u) {
    union { unsigned int i; float f; } z; z.i = ((unsigned int)u) << 16; return z.f;
}
__device__ __forceinline__ float u2f_lo(unsigned int u) {
    union { unsigned int i; float f; } z; z.i = u << 16; return z.f;
}
__device__ __forceinline__ float u2f_hi(unsigned int u) {
    union { unsigned int i; float f; } z; z.i = u & 0xffff0000u; return z.f;
}
__device__ __forceinline__ unsigned short f2us(float f) {
    bf16 b = __float2bfloat16(f);
    return *(unsigned short*)&b;
}
__device__ __forceinline__ float ld(const void* p, int i, int isbf) {
    if (isbf) return us2f(((const unsigned short*)p)[i]);
    return ((const float*)p)[i];
}
__device__ __forceinline__ float lrexp(float v) {
    v = v > 0.f ? v : SLOPE * v;
    return __expf(fminf(v, 60.f));
}

// bf16-vs-fp32 input sniffer (see R2 notes).
__global__ __launch_bounds__(256) void k_sniff(const void* __restrict__ h, int* __restrict__ flag) {
    __shared__ int cnt;
    if (threadIdx.x == 0) cnt = 0;
    __syncthreads();
    const unsigned short* u = (const unsigned short*)h;
    unsigned short v = u[2 * threadIdx.x];
    int ef = (v >> 7) & 0xFF;
    if (ef >= 100 && ef <= 150) atomicAdd(&cnt, 1);
    __syncthreads();
    if (threadIdx.x == 0) flag[0] = (cnt >= 192) ? 1 : 0;
}

// Build bf16 weight buffers once per launch:
// Wxb[64][272]: cols 0..255 = W_gat; 256+h = W_gat_head_h @ a_l[h]; 260+h = @ a_r[h]; 264..271 = 0.
// Wrb[64][64] = bf16(W_res).
__global__ __launch_bounds__(256) void k_prep(const void* __restrict__ Wg,
                                              const void* __restrict__ al,
                                              const void* __restrict__ ar,
                                              const void* __restrict__ Wr,
                                              const int* __restrict__ flag,
                                              unsigned short* __restrict__ Wxb,
                                              unsigned short* __restrict__ Wrb) {
    const int isbf = flag[0];
    int t = threadIdx.x, b = blockIdx.x;
    if (b < 16) {
#pragma unroll
        for (int q = 0; q < 4; q++) {
            int idx = b * 1024 + q * 256 + t;
            int k = idx >> 8, c = idx & 255;
            Wxb[k * 272 + c] = f2us(ld(Wg, idx, isbf));
        }
    } else if (b == 16) {
#pragma unroll
        for (int d2 = 0; d2 < 2; d2++) {
            int idx = d2 * 256 + t;          // 0..511: lr*256 + hh*64 + k
            int k = idx & 63, hh = (idx >> 6) & 3, lr = idx >> 8;
            const void* a = lr ? ar : al;
            float s = 0.f;
            for (int d = 0; d < 64; d++)
                s += ld(Wg, k * 256 + hh * 64 + d, isbf) * ld(a, hh * 64 + d, isbf);
            Wxb[k * 272 + 256 + lr * 4 + hh] = f2us(s);
        }
        if (t < 64)
            for (int c = 264; c < 272; c++) Wxb[t * 272 + c] = 0;
    } else {
#pragma unroll
        for (int q = 0; q < 16; q++) {
            int idx = q * 256 + t;
            Wrb[idx] = f2us(ld(Wr, idx, isbf));
        }
    }
}

// ---- CSR build ----
__global__ __launch_bounds__(256) void k_hist(const int* __restrict__ dst, int* __restrict__ deg) {
    int e = blockIdx.x * 256 + threadIdx.x;
    if (e < N_EDGES) atomicAdd(&deg[dst[e]], 1);
}

__global__ __launch_bounds__(1024) void k_scan(const int* __restrict__ deg,
                                               int* __restrict__ rowstart,
                                               int* __restrict__ cursor) {
    __shared__ int ssum[1024];
    int t = threadIdx.x;
    int base = t * 20;
    int local[20];
    int s = 0;
#pragma unroll
    for (int i = 0; i < 20; i++) {
        int v = (base + i < N_NODES) ? deg[base + i] : 0;
        local[i] = s;
        s += v;
    }
    ssum[t] = s;
    __syncthreads();
    for (int off = 1; off < 1024; off <<= 1) {
        int v = (t >= off) ? ssum[t - off] : 0;
        __syncthreads();
        if (t >= off) ssum[t] += v;
        __syncthreads();
    }
    int prev = (t == 0) ? 0 : ssum[t - 1];
#pragma unroll
    for (int i = 0; i < 20; i++) {
        if (base + i < N_NODES) {
            int v = prev + local[i];
            rowstart[base + i] = v;
            cursor[base + i] = v;
        }
    }
    if (t == 1023) rowstart[N_NODES] = ssum[1023];
}

__global__ __launch_bounds__(256) void k_scatter(const int* __restrict__ src,
                                                 const int* __restrict__ dst,
                                                 int* __restrict__ cursor,
                                                 int* __restrict__ csrc) {
    int e = blockIdx.x * 256 + threadIdx.x;
    if (e >= N_EDGES) return;
    int pos = atomicAdd(&cursor[dst[e]], 1);
    csrc[pos] = src[e];
}

// x[row=n*2+b][0..63] = h[b][n][:] @ W_enc + b_enc
__global__ __launch_bounds__(256) void k_enc(const void* __restrict__ h,
                                             const void* __restrict__ W,
                                             const void* __restrict__ bias,
                                             float* __restrict__ x,
                                             const int* __restrict__ flag) {
    const int isbf = flag[0];
    __shared__ float sW[IN_DIM * HID];
    __shared__ float sB[HID];
    int t = threadIdx.x;
    for (int i = t; i < IN_DIM * HID; i += 256) sW[i] = ld(W, i, isbf);
    if (t < HID) sB[t] = ld(bias, t, isbf);
    __syncthreads();
    int row = blockIdx.x * 4 + (t >> 6);
    int col = t & 63;
    if (row >= ROWS) return;
    int n = row >> 1, b = row & 1;
    size_t hbase = (size_t)(b * N_NODES + n) * IN_DIM;
    float acc = sB[col];
#pragma unroll
    for (int k = 0; k < IN_DIM; k++) acc += ld(h, hbase + k, isbf) * sW[k * HID + col];
    x[(size_t)row * HID + col] = acc;
}

// MFMA gat_proj using precomputed Wxb[64][272] (el/er folded in as cols 256..263).
// Block = 64 rows; wave w = head w for ft cols; ct=4 tile computed by all waves,
// stored by wave 0 only.
__global__ __launch_bounds__(256) void k_gat_proj(const float* __restrict__ x,
                                                  const unsigned short* __restrict__ Wxb,
                                                  unsigned int* __restrict__ ftb32,
                                                  float* __restrict__ el,
                                                  float* __restrict__ er) {
    int t = threadIdx.x;
    int w = t >> 6;
    int lane = t & 63;
    int quad = lane >> 4;
    int m16 = lane & 15;
    int row0 = blockIdx.x * 64;

    v8s Bf[5][2];
#pragma unroll
    for (int ct = 0; ct < 5; ct++) {
        int gcol = (ct < 4) ? (w * 64 + ct * 16 + m16) : (256 + m16);
#pragma unroll
        for (int ks = 0; ks < 2; ks++) {
#pragma unroll
            for (int j = 0; j < 8; j++) {
                int k = ks * 32 + quad * 8 + j;
                Bf[ct][ks][j] = (short)Wxb[k * 272 + gcol];
            }
        }
    }

    v4f acc[4][5];
#pragma unroll
    for (int rt = 0; rt < 4; rt++)
#pragma unroll
        for (int ct = 0; ct < 5; ct++)
            acc[rt][ct] = (v4f)(0.f);

#pragma unroll
    for (int ks = 0; ks < 2; ks++) {
#pragma unroll
        for (int rt = 0; rt < 4; rt++) {
            int grow = row0 + rt * 16 + m16;
            const float4* xp = (const float4*)(x + (size_t)grow * 64 + ks * 32 + quad * 8);
            float4 xa = xp[0], xb = xp[1];
            v8s Af;
            Af[0] = (short)f2us(xa.x); Af[1] = (short)f2us(xa.y);
            Af[2] = (short)f2us(xa.z); Af[3] = (short)f2us(xa.w);
            Af[4] = (short)f2us(xb.x); Af[5] = (short)f2us(xb.y);
            Af[6] = (short)f2us(xb.z); Af[7] = (short)f2us(xb.w);
#pragma unroll
            for (int ct = 0; ct < 5; ct++)
                acc[rt][ct] = __builtin_amdgcn_mfma_f32_16x16x32_bf16(Af, Bf[ct][ks], acc[rt][ct], 0, 0, 0);
        }
    }

    // packed batch-pair ft stores straight from C-frags
#pragma unroll
    for (int rt = 0; rt < 4; rt++) {
        int sbase = (row0 + rt * 16 + quad * 4) >> 1;
#pragma unroll
        for (int ct = 0; ct < 4; ct++) {
            int gcol = w * 64 + ct * 16 + m16;
            unsigned int u01 = (unsigned int)f2us(acc[rt][ct][0]) | ((unsigned int)f2us(acc[rt][ct][1]) << 16);
            unsigned int u23 = (unsigned int)f2us(acc[rt][ct][2]) | ((unsigned int)f2us(acc[rt][ct][3]) << 16);
            ftb32[(size_t)sbase * 256 + gcol] = u01;
            ftb32[(size_t)(sbase + 1) * 256 + gcol] = u23;
        }
    }
    // el/er from the extra tile (wave 0 only; cols 256..259=el heads, 260..263=er heads)
    if (w == 0 && m16 < 8) {
#pragma unroll
        for (int rt = 0; rt < 4; rt++) {
#pragma unroll
            for (int r = 0; r < 4; r++) {
                int grow = row0 + rt * 16 + quad * 4 + r;
                float v = acc[rt][4][r];
                if (m16 < 4) el[grow * 4 + m16] = v;
                else         er[grow * 4 + (m16 - 4)] = v;
            }
        }
    }
}

// One block per dst node, both batches. uint2 gathers: lane covers 2 col-pairs;
// wave-pair wp handles edges of parity wp within each 64-edge chunk.
__global__ __launch_bounds__(256) void k_agg(const int* __restrict__ rowstart,
                                             const int* __restrict__ csrc,
                                             const float* __restrict__ el,
                                             const float* __restrict__ er,
                                             const unsigned int* __restrict__ ftb32,
                                             const void* __restrict__ bg,
                                             float* __restrict__ aggm,
                                             const int* __restrict__ flag) {
    const int isbf = flag[0];
    int n = blockIdx.x;
    int t = threadIdx.x;
    int wp = t >> 7;          // wave-pair
    int i = t & 127;          // col-pair index: cols 2i, 2i+1
    int h = i >> 5;           // head of both cols
    int beg = rowstart[n], end = rowstart[n + 1];
    __shared__ int sC[64];
    __shared__ float2 sWe[256];
    __shared__ float4 red[256];
    __shared__ float2 wsS[2][4];
    float acc00 = 0.f, acc01 = 0.f, acc10 = 0.f, acc11 = 0.f;
    float ws0 = 0.f, ws1 = 0.f;
    for (int p0 = beg; p0 < end; p0 += 64) {
        int cnt = min(64, end - p0);
        __syncthreads();
        if (t < cnt * 4) {
            int e = t >> 2, hh = t & 3;
            int s = csrc[p0 + e];
            if (hh == 0) sC[e] = s;
            float e0 = el[s * 8 + hh];
            float e1 = el[s * 8 + 4 + hh];
            float r0 = er[n * 8 + hh];
            float r1 = er[n * 8 + 4 + hh];
            sWe[t] = make_float2(lrexp(e0 + r0), lrexp(e1 + r1));
        }
        __syncthreads();
#pragma unroll 4
        for (int e = wp; e < cnt; e += 2) {
            int s = sC[e];
            float2 we = sWe[e * 4 + h];
            uint2 q = *(const uint2*)(ftb32 + (size_t)s * 256 + 2 * i);
            acc00 += we.x * u2f_lo(q.x);
            acc01 += we.y * u2f_hi(q.x);
            acc10 += we.x * u2f_lo(q.y);
            acc11 += we.y * u2f_hi(q.y);
            ws0 += we.x;
            ws1 += we.y;
        }
    }
    red[wp * 128 + i] = make_float4(acc00, acc01, acc10, acc11);
    if ((i & 31) == 0) wsS[wp][h] = make_float2(ws0, ws1);
    __syncthreads();
    if (t < 64) {
        int deg = end - beg;
        float m0 = 0.f, m1 = 0.f;
#pragma unroll
        for (int hh = 0; hh < 4; hh++) {
            int col = hh * 64 + t;
            int ii = col >> 1, sub = col & 1;
            float4 r0 = red[ii], r1 = red[128 + ii];
            float a0 = (sub ? r0.z : r0.x) + (sub ? r1.z : r1.x);
            float a1 = (sub ? r0.w : r0.y) + (sub ? r1.w : r1.y);
            float w0 = wsS[0][hh].x + wsS[1][hh].x;
            float w1 = wsS[0][hh].y + wsS[1][hh].y;
            float bgv = ld(bg, col, isbf);
            m0 += (deg > 0 ? a0 / w0 : 0.f) + bgv;
            m1 += (deg > 0 ? a1 / w1 : 0.f) + bgv;
        }
        aggm[(size_t)(n * 2 + 0) * HID + t] = 0.25f * m0;
        aggm[(size_t)(n * 2 + 1) * HID + t] = 0.25f * m1;
    }
}

// MFMA update: x = elu( aggm + x @ W_res + b_res ), in-place; Wrb pre-converted bf16.
__global__ __launch_bounds__(256) void k_update(float* __restrict__ x,
                                                const float* __restrict__ aggm,
                                                const unsigned short* __restrict__ Wrb,
                                                const void* __restrict__ br,
                                                const int* __restrict__ flag) {
    const int isbf = flag[0];
    int t = threadIdx.x;
    int w = t >> 6;
    int lane = t & 63;
    int quad = lane >> 4;
    int m16 = lane & 15;
    int row0 = blockIdx.x * 64;

    v8s Bf[4][2];
#pragma unroll
    for (int ct = 0; ct < 4; ct++) {
        int col = ct * 16 + m16;
#pragma unroll
        for (int ks = 0; ks < 2; ks++) {
#pragma unroll
            for (int j = 0; j < 8; j++) {
                int k = ks * 32 + quad * 8 + j;
                Bf[ct][ks][j] = (short)Wrb[k * 64 + col];
            }
        }
    }

    v4f acc[4];
#pragma unroll
    for (int ct = 0; ct < 4; ct++) acc[ct] = (v4f)(0.f);

    int arow = row0 + w * 16 + m16;
#pragma unroll
    for (int ks = 0; ks < 2; ks++) {
        const float4* xp = (const float4*)(x + (size_t)arow * 64 + ks * 32 + quad * 8);
        float4 xa = xp[0], xb = xp[1];
        v8s Af;
        Af[0] = (short)f2us(xa.x); Af[1] = (short)f2us(xa.y);
        Af[2] = (short)f2us(xa.z); Af[3] = (short)f2us(xa.w);
        Af[4] = (short)f2us(xb.x); Af[5] = (short)f2us(xb.y);
        Af[6] = (short)f2us(xb.z); Af[7] = (short)f2us(xb.w);
#pragma unroll
        for (int ct = 0; ct < 4; ct++)
            acc[ct] = __builtin_amdgcn_mfma_f32_16x16x32_bf16(Af, Bf[ct][ks], acc[ct], 0, 0, 0);
    }

#pragma unroll
    for (int ct = 0; ct < 4; ct++) {
        int col = ct * 16 + m16;
        float bv = ld(br, col, isbf);
#pragma unroll
        for (int r = 0; r < 4; r++) {
            int row = row0 + w * 16 + quad * 4 + r;
            float v = acc[ct][r] + bv + aggm[(size_t)row * 64 + col];
            x[(size_t)row * 64 + col] = v > 0.f ? v : expm1f(v);
        }
    }
}

// out[b][n][o] = x[row=n*2+b] @ W_dec + b_dec ; output dtype follows input dtype
__global__ __launch_bounds__(256) void k_dec(const float* __restrict__ x,
                                             const void* __restrict__ Wd,
                                             const void* __restrict__ bd,
                                             void* __restrict__ out,
                                             const int* __restrict__ flag) {
    const int isbf = flag[0];
    __shared__ float sW[HID * OUT_DIM];
    __shared__ float sB[OUT_DIM];
    int t = threadIdx.x;
    for (int i = t; i < HID * OUT_DIM; i += 256) sW[i] = ld(Wd, i, isbf);
    if (t < OUT_DIM) sB[t] = ld(bd, t, isbf);
    __syncthreads();
    int gid = blockIdx.x * 256 + t;
    if (gid >= ROWS * OUT_DIM) return;
    int row = gid >> 3, o = gid & 7;
    int n = row >> 1, b = row & 1;
    float acc = sB[o];
#pragma unroll
    for (int k = 0; k < HID; k++) acc += x[(size_t)row * HID + k] * sW[k * OUT_DIM + o];
    size_t oi = (size_t)(b * N_NODES + n) * OUT_DIM + o;
    if (isbf) ((unsigned short*)out)[oi] = f2us(acc);
    else      ((float*)out)[oi] = acc;
}

extern "C" void kernel_launch(void* const* d_in, const int* in_sizes, int n_in,
                              void* d_out, int out_size, void* d_ws, size_t ws_size,
                              hipStream_t stream) {
    const void* h     = d_in[0];
    const int*  ei    = (const int*)d_in[1];
    const void* W_enc = d_in[2];
    const void* b_enc = d_in[3];
    const void* W_gat = d_in[4];
    const void* a_l   = d_in[5];
    const void* a_r   = d_in[6];
    const void* b_gat = d_in[7];
    const void* W_res = d_in[8];
    const void* b_res = d_in[9];
    const void* W_dec = d_in[10];
    const void* b_dec = d_in[11];

    float* ws = (float*)d_ws;
    int*   flag     = (int*)(ws + WS_FLAG);
    float* x        = ws + WS_X;
    unsigned int* ftb32 = (unsigned int*)(ws + WS_FT);
    float* el       = ws + WS_EL;
    float* er       = ws + WS_ER;
    float* aggm     = ws + WS_AGGM;
    int*   deg      = (int*)(ws + WS_DEG);
    int*   rowstart = (int*)(ws + WS_ROWSTART);
    int*   cursor   = (int*)(ws + WS_CUR);
    int*   csrc     = (int*)(ws + WS_CSRC);
    unsigned short* Wxb = (unsigned short*)(ws + WS_WXB);
    unsigned short* Wrb = (unsigned short*)(ws + WS_WRB);

    const int* src = ei;
    const int* dst = ei + N_EDGES;

    k_sniff<<<1, 256, 0, stream>>>(h, flag);
    k_prep<<<18, 256, 0, stream>>>(W_gat, a_l, a_r, W_res, flag, Wxb, Wrb);
    k_enc<<<ROWS / 4, 256, 0, stream>>>(h, W_enc, b_enc, x, flag);

    hipMemsetAsync(deg, 0, N_NODES * sizeof(int), stream);
    k_hist<<<(N_EDGES + 255) / 256, 256, 0, stream>>>(dst, deg);
    k_scan<<<1, 1024, 0, stream>>>(deg, rowstart, cursor);
    k_scatter<<<(N_EDGES + 255) / 256, 256, 0, stream>>>(src, dst, cursor, csrc);

    for (int r = 0; r < 2; r++) {
        k_gat_proj<<<ROWS / 64, 256, 0, stream>>>(x, Wxb, ftb32, el, er);
        k_agg<<<N_NODES, 256, 0, stream>>>(rowstart, csrc, el, er, ftb32, b_gat, aggm, flag);
        k_update<<<ROWS / 64, 256, 0, stream>>>(x, aggm, Wrb, b_res, flag);
    }
    k_dec<<<(ROWS * OUT_DIM + 255) / 256, 256, 0, stream>>>(x, W_dec, b_dec, d_out, flag);
}

// Round 9
// 305.584 us; speedup vs baseline: 16.3358x; 1.1159x over previous
//
#include <hip/hip_runtime.h>
#include <hip/hip_bf16.h>

#define N_NODES 20000
#define N_EDGES 320000
#define BATCH 2
#define IN_DIM 32
#define HID 64
#define HEADS 4
#define OUT_DIM 8
#define ROWS (N_NODES * BATCH) /* 40000 */
#define SLOPE 0.2f

typedef __hip_bfloat16 bf16;
typedef short v8s __attribute__((ext_vector_type(8)));
typedef float v4f __attribute__((ext_vector_type(4)));

// ---- workspace layout (float slots) ----
#define WS_FLAG 0
#define WS_X        64        /* 2,560,000 floats */
#define WS_XB32     2560064   /* 20000*64 u32: packed bf16 (b0,b1) x table */
#define WS_AGGXB    3840064   /* 20000*256 u32: packed normalized head-aggregates */
#define WS_EL       8960064   /* 160,000 */
#define WS_ER       9120064   /* 160,000 */
#define WS_DEG      9280064   /* 20,032 ints */
#define WS_ROWSTART 9300096   /* 20,032 ints (20001 used) */
#define WS_CUR      9320128   /* 20,032 ints */
#define WS_CSRC     9340160   /* 320,000 ints */
#define WS_WGBPK    9660160   /* 16384 u16 */
#define WS_WRESBPK  9668352   /* 4096 u16 */
#define WS_WX8PK    9670400   /* 1024 u16 */
#define WS_BGM      9670912   /* 64 floats */
#define WS_END      9670976   /* ~38.7 MB */

__device__ __forceinline__ float us2f(unsigned short u) {
    union { unsigned int i; float f; } z; z.i = ((unsigned int)u) << 16; return z.f;
}
__device__ __forceinline__ float u2f_lo(unsigned int u) {
    union { unsigned int i; float f; } z; z.i = u << 16; return z.f;
}
__device__ __forceinline__ float u2f_hi(unsigned int u) {
    union { unsigned int i; float f; } z; z.i = u & 0xffff0000u; return z.f;
}
__device__ __forceinline__ unsigned short f2us(float f) {
    bf16 b = __float2bfloat16(f);
    return *(unsigned short*)&b;
}
__device__ __forceinline__ float ld(const void* p, int i, int isbf) {
    if (isbf) return us2f(((const unsigned short*)p)[i]);
    return ((const float*)p)[i];
}
__device__ __forceinline__ float lrexp(float v) {
    v = v > 0.f ? v : SLOPE * v;
    return __expf(fminf(v, 60.f));
}

// bf16-vs-fp32 input sniffer (see R2 notes).
__global__ __launch_bounds__(256) void k_sniff(const void* __restrict__ h, int* __restrict__ flag) {
    __shared__ int cnt;
    if (threadIdx.x == 0) cnt = 0;
    __syncthreads();
    const unsigned short* u = (const unsigned short*)h;
    unsigned short v = u[2 * threadIdx.x];
    int ef = (v >> 7) & 0xFF;
    if (ef >= 100 && ef <= 150) atomicAdd(&cnt, 1);
    __syncthreads();
    if (threadIdx.x == 0) flag[0] = (cnt >= 192) ? 1 : 0;
}

// Pack B-operands into MFMA-fragment-native layout (one 16B load per frag).
__global__ __launch_bounds__(256) void k_prep(const void* __restrict__ Wg,
                                              const void* __restrict__ al,
                                              const void* __restrict__ ar,
                                              const void* __restrict__ Wr,
                                              const void* __restrict__ bg,
                                              const int* __restrict__ flag,
                                              unsigned short* __restrict__ WgBpk,
                                              unsigned short* __restrict__ WresBpk,
                                              unsigned short* __restrict__ Wx8pk,
                                              float* __restrict__ bgm) {
    const int isbf = flag[0];
    int t = threadIdx.x, b = blockIdx.x;
    if (b < 16) {
#pragma unroll
        for (int q = 0; q < 4; q++) {
            int idx = b * 1024 + q * 256 + t;
            int j = idx & 7, m16 = (idx >> 3) & 15, quad = (idx >> 7) & 3;
            int ks = (idx >> 9) & 1, ct = (idx >> 10) & 3, hh = (idx >> 12) & 3;
            int k = ks * 32 + quad * 8 + j;
            int c = hh * 64 + ct * 16 + m16;
            WgBpk[idx] = f2us(ld(Wg, k * 256 + c, isbf));
        }
    } else if (b == 16) {
#pragma unroll
        for (int q = 0; q < 4; q++) {
            int idx = q * 256 + t;
            int j = idx & 7, m16 = (idx >> 3) & 15, quad = (idx >> 7) & 3;
            int ks = (idx >> 9) & 1;
            int k = ks * 32 + quad * 8 + j;
            float v = 0.f;
            if (m16 < 8) {
                int hh = m16 & 3, lr = m16 >> 2;
                const void* a = lr ? ar : al;
                for (int d = 0; d < 64; d++)
                    v += ld(Wg, k * 256 + hh * 64 + d, isbf) * ld(a, hh * 64 + d, isbf);
            }
            Wx8pk[idx] = f2us(v);
        }
        if (t < 64) {
            float s = 0.f;
            for (int hh = 0; hh < 4; hh++) s += ld(bg, hh * 64 + t, isbf);
            bgm[t] = 0.25f * s;
        }
    } else {
#pragma unroll
        for (int q = 0; q < 16; q++) {
            int idx = q * 256 + t;
            int j = idx & 7, m16 = (idx >> 3) & 15, quad = (idx >> 7) & 3;
            int ks = (idx >> 9) & 1, ct = (idx >> 10) & 3;
            int k = ks * 32 + quad * 8 + j;
            WresBpk[idx] = f2us(ld(Wr, k * 64 + ct * 16 + m16, isbf));
        }
    }
}

// ---- CSR build ----
__global__ __launch_bounds__(256) void k_hist(const int* __restrict__ dst, int* __restrict__ deg) {
    int e = blockIdx.x * 256 + threadIdx.x;
    if (e < N_EDGES) atomicAdd(&deg[dst[e]], 1);
}

__global__ __launch_bounds__(1024) void k_scan(const int* __restrict__ deg,
                                               int* __restrict__ rowstart,
                                               int* __restrict__ cursor) {
    __shared__ int ssum[1024];
    int t = threadIdx.x;
    int base = t * 20;
    int local[20];
    int s = 0;
#pragma unroll
    for (int i = 0; i < 20; i++) {
        int v = (base + i < N_NODES) ? deg[base + i] : 0;
        local[i] = s;
        s += v;
    }
    ssum[t] = s;
    __syncthreads();
    for (int off = 1; off < 1024; off <<= 1) {
        int v = (t >= off) ? ssum[t - off] : 0;
        __syncthreads();
        if (t >= off) ssum[t] += v;
        __syncthreads();
    }
    int prev = (t == 0) ? 0 : ssum[t - 1];
#pragma unroll
    for (int i = 0; i < 20; i++) {
        if (base + i < N_NODES) {
            int v = prev + local[i];
            rowstart[base + i] = v;
            cursor[base + i] = v;
        }
    }
    if (t == 1023) rowstart[N_NODES] = ssum[1023];
}

__global__ __launch_bounds__(256) void k_scatter(const int* __restrict__ src,
                                                 const int* __restrict__ dst,
                                                 int* __restrict__ cursor,
                                                 int* __restrict__ csrc) {
    int e = blockIdx.x * 256 + threadIdx.x;
    if (e >= N_EDGES) return;
    int pos = atomicAdd(&cursor[dst[e]], 1);
    csrc[pos] = src[e];
}

// x[row=n*2+b][0..63] = h[b][n][:] @ W_enc + b_enc
__global__ __launch_bounds__(256) void k_enc(const void* __restrict__ h,
                                             const void* __restrict__ W,
                                             const void* __restrict__ bias,
                                             float* __restrict__ x,
                                             const int* __restrict__ flag) {
    const int isbf = flag[0];
    __shared__ float sW[IN_DIM * HID];
    __shared__ float sB[HID];
    int t = threadIdx.x;
    for (int i = t; i < IN_DIM * HID; i += 256) sW[i] = ld(W, i, isbf);
    if (t < HID) sB[t] = ld(bias, t, isbf);
    __syncthreads();
    int row = blockIdx.x * 4 + (t >> 6);
    int col = t & 63;
    if (row >= ROWS) return;
    int n = row >> 1, b = row & 1;
    size_t hbase = (size_t)(b * N_NODES + n) * IN_DIM;
    float acc = sB[col];
#pragma unroll
    for (int k = 0; k < IN_DIM; k++) acc += ld(h, hbase + k, isbf) * sW[k * HID + col];
    x[(size_t)row * HID + col] = acc;
}

// el/er + packed-x table from fp32 x. Block = 64 rows; wave w = rows w*16..+15.
__global__ __launch_bounds__(256) void k_el(const float* __restrict__ x,
                                            const unsigned short* __restrict__ Wx8pk,
                                            float* __restrict__ el,
                                            float* __restrict__ er,
                                            unsigned int* __restrict__ xb32) {
    int t = threadIdx.x;
    int w = t >> 6, lane = t & 63, quad = lane >> 4, m16 = lane & 15;
    int row0 = blockIdx.x * 64;
    v4f e8 = (v4f)(0.f);
#pragma unroll
    for (int ks = 0; ks < 2; ks++) {
        int arow = row0 + w * 16 + m16;
        const float4* xp = (const float4*)(x + (size_t)arow * 64 + ks * 32 + quad * 8);
        float4 xa = xp[0], xb = xp[1];
        v8s Af;
        Af[0] = (short)f2us(xa.x); Af[1] = (short)f2us(xa.y);
        Af[2] = (short)f2us(xa.z); Af[3] = (short)f2us(xa.w);
        Af[4] = (short)f2us(xb.x); Af[5] = (short)f2us(xb.y);
        Af[6] = (short)f2us(xb.z); Af[7] = (short)f2us(xb.w);
        v8s Bf = *(const v8s*)(Wx8pk + (((ks * 4 + quad) << 7) + (m16 << 3)));
        e8 = __builtin_amdgcn_mfma_f32_16x16x32_bf16(Af, Bf, e8, 0, 0, 0);
    }
    if (m16 < 8) {
#pragma unroll
        for (int r = 0; r < 4; r++) {
            int grow = row0 + w * 16 + quad * 4 + r;
            float v = e8[r];
            if (m16 < 4) el[grow * 4 + m16] = v;
            else         er[grow * 4 + (m16 - 4)] = v;
        }
    }
#pragma unroll
    for (int i = 0; i < 8; i++) {
        int idx = i * 256 + t;
        int j = idx >> 6, c = idx & 63;
        float f0 = x[(size_t)(row0 + 2 * j) * 64 + c];
        float f1 = x[(size_t)(row0 + 2 * j + 1) * 64 + c];
        xb32[(size_t)(blockIdx.x * 32 + j) * 64 + c] =
            (unsigned int)f2us(f0) | ((unsigned int)f2us(f1) << 16);
    }
}

// Edge phase: block per dst node. Gather packed x (256 B/edge), 8 weighted sums.
__global__ __launch_bounds__(256) void k_agg(const int* __restrict__ rowstart,
                                             const int* __restrict__ csrc,
                                             const float* __restrict__ el,
                                             const float* __restrict__ er,
                                             const unsigned int* __restrict__ xb32,
                                             unsigned int* __restrict__ aggxb) {
    int n = blockIdx.x;
    int t = threadIdx.x;
    int g = t >> 6;
    int c = t & 63;
    int beg = rowstart[n], end = rowstart[n + 1];
    __shared__ int sC[64];
    __shared__ float2 sWe[256];
    __shared__ float sWs[8];
    __shared__ float red[2048];
    if (t < 8) sWs[t] = 0.f;
    float a00 = 0.f, a01 = 0.f, a10 = 0.f, a11 = 0.f;
    float a20 = 0.f, a21 = 0.f, a30 = 0.f, a31 = 0.f;
    for (int p0 = beg; p0 < end; p0 += 64) {
        int cnt = min(64, end - p0);
        __syncthreads();
        if (t < cnt * 4) {
            int e = t >> 2, hh = t & 3;
            int s = csrc[p0 + e];
            if (hh == 0) sC[e] = s;
            float w0 = lrexp(el[s * 8 + hh] + er[n * 8 + hh]);
            float w1 = lrexp(el[s * 8 + 4 + hh] + er[n * 8 + 4 + hh]);
            sWe[t] = make_float2(w0, w1);
            atomicAdd(&sWs[hh * 2 + 0], w0);
            atomicAdd(&sWs[hh * 2 + 1], w1);
        }
        __syncthreads();
        for (int e = g; e < cnt; e += 4) {
            int s = sC[e];
            unsigned int q = xb32[(size_t)s * 64 + c];
            float xlo = u2f_lo(q), xhi = u2f_hi(q);
            float2 w0 = sWe[e * 4 + 0];
            float2 w1 = sWe[e * 4 + 1];
            float2 w2 = sWe[e * 4 + 2];
            float2 w3 = sWe[e * 4 + 3];
            a00 += w0.x * xlo; a01 += w0.y * xhi;
            a10 += w1.x * xlo; a11 += w1.y * xhi;
            a20 += w2.x * xlo; a21 += w2.y * xhi;
            a30 += w3.x * xlo; a31 += w3.y * xhi;
        }
    }
    red[(g * 8 + 0) * 64 + c] = a00; red[(g * 8 + 1) * 64 + c] = a01;
    red[(g * 8 + 2) * 64 + c] = a10; red[(g * 8 + 3) * 64 + c] = a11;
    red[(g * 8 + 4) * 64 + c] = a20; red[(g * 8 + 5) * 64 + c] = a21;
    red[(g * 8 + 6) * 64 + c] = a30; red[(g * 8 + 7) * 64 + c] = a31;
    __syncthreads();
    int h = t >> 6;
    float s0 = 0.f, s1 = 0.f;
#pragma unroll
    for (int g2 = 0; g2 < 4; g2++) {
        s0 += red[(g2 * 8 + h * 2 + 0) * 64 + c];
        s1 += red[(g2 * 8 + h * 2 + 1) * 64 + c];
    }
    float w0 = sWs[h * 2 + 0], w1 = sWs[h * 2 + 1];
    float v0 = (w0 > 0.f) ? s0 / (4.f * w0) : 0.f;
    float v1 = (w1 > 0.f) ? s1 / (4.f * w1) : 0.f;
    aggxb[(size_t)n * 256 + h * 64 + c] =
        (unsigned int)f2us(v0) | ((unsigned int)f2us(v1) << 16);
}

// Fused update: x = elu( sum_h(Ah_norm/4 @ Wg_h) + bgm + x @ W_res + b_res ).
__global__ __launch_bounds__(256) void k_update(float* __restrict__ x,
                                                const unsigned int* __restrict__ aggxb,
                                                const unsigned short* __restrict__ WgBpk,
                                                const unsigned short* __restrict__ WresBpk,
                                                const unsigned short* __restrict__ Wx8pk,
                                                const void* __restrict__ br,
                                                const float* __restrict__ bgm,
                                                unsigned int* __restrict__ xb32,
                                                float* __restrict__ el,
                                                float* __restrict__ er,
                                                const int* __restrict__ flag,
                                                int emit) {
    const int isbf = flag[0];
    __shared__ unsigned short sXb[64 * 64];
    int t = threadIdx.x;
    int w = t >> 6, lane = t & 63, quad = lane >> 4, m16 = lane & 15;
    int row0 = blockIdx.x * 64;
    int grow = row0 + w * 16 + m16;
    int nd = grow >> 1;
    unsigned sh = (grow & 1) * 16;

    v4f acc[4];
#pragma unroll
    for (int ct = 0; ct < 4; ct++) acc[ct] = (v4f)(0.f);

#pragma unroll
    for (int hh = 0; hh < 4; hh++) {
#pragma unroll
        for (int ks = 0; ks < 2; ks++) {
            const uint4* ap = (const uint4*)(aggxb + (size_t)nd * 256 + hh * 64 + ks * 32 + quad * 8);
            uint4 qa = ap[0], qb = ap[1];
            v8s Af;
            Af[0] = (short)((qa.x >> sh) & 0xffffu);
            Af[1] = (short)((qa.y >> sh) & 0xffffu);
            Af[2] = (short)((qa.z >> sh) & 0xffffu);
            Af[3] = (short)((qa.w >> sh) & 0xffffu);
            Af[4] = (short)((qb.x >> sh) & 0xffffu);
            Af[5] = (short)((qb.y >> sh) & 0xffffu);
            Af[6] = (short)((qb.z >> sh) & 0xffffu);
            Af[7] = (short)((qb.w >> sh) & 0xffffu);
#pragma unroll
            for (int ct = 0; ct < 4; ct++) {
                v8s Bf = *(const v8s*)(WgBpk + ((hh << 12) | (ct << 10) | (ks << 9) | (quad << 7) | (m16 << 3)));
                acc[ct] = __builtin_amdgcn_mfma_f32_16x16x32_bf16(Af, Bf, acc[ct], 0, 0, 0);
            }
        }
    }
#pragma unroll
    for (int ks = 0; ks < 2; ks++) {
        const float4* xp = (const float4*)(x + (size_t)grow * 64 + ks * 32 + quad * 8);
        float4 xa = xp[0], xb = xp[1];
        v8s Af;
        Af[0] = (short)f2us(xa.x); Af[1] = (short)f2us(xa.y);
        Af[2] = (short)f2us(xa.z); Af[3] = (short)f2us(xa.w);
        Af[4] = (short)f2us(xb.x); Af[5] = (short)f2us(xb.y);
        Af[6] = (short)f2us(xb.z); Af[7] = (short)f2us(xb.w);
#pragma unroll
        for (int ct = 0; ct < 4; ct++) {
            v8s Bf = *(const v8s*)(WresBpk + ((ct << 10) | (ks << 9) | (quad << 7) | (m16 << 3)));
            acc[ct] = __builtin_amdgcn_mfma_f32_16x16x32_bf16(Af, Bf, acc[ct], 0, 0, 0);
        }
    }

#pragma unroll
    for (int ct = 0; ct < 4; ct++) {
        int col = ct * 16 + m16;
        float bv = ld(br, col, isbf) + bgm[col];
        float vr[4];
#pragma unroll
        for (int r = 0; r < 4; r++) {
            int rloc = w * 16 + quad * 4 + r;
            float v = acc[ct][r] + bv;
            v = v > 0.f ? v : expm1f(v);
            vr[r] = v;
            x[(size_t)(row0 + rloc) * 64 + col] = v;
            sXb[rloc * 64 + col] = f2us(v);
        }
        if (emit) {
            int nd0 = (row0 + w * 16 + quad * 4) >> 1;
            xb32[(size_t)nd0 * 64 + col] =
                (unsigned int)f2us(vr[0]) | ((unsigned int)f2us(vr[1]) << 16);
            xb32[(size_t)(nd0 + 1) * 64 + col] =
                (unsigned int)f2us(vr[2]) | ((unsigned int)f2us(vr[3]) << 16);
        }
    }
    if (emit) {
        __syncthreads();
        v4f e8 = (v4f)(0.f);
#pragma unroll
        for (int ks = 0; ks < 2; ks++) {
            v8s Af = *(const v8s*)(sXb + (w * 16 + m16) * 64 + ks * 32 + quad * 8);
            v8s Bf = *(const v8s*)(Wx8pk + (((ks * 4 + quad) << 7) + (m16 << 3)));
            e8 = __builtin_amdgcn_mfma_f32_16x16x32_bf16(Af, Bf, e8, 0, 0, 0);
        }
        if (m16 < 8) {
#pragma unroll
            for (int r = 0; r < 4; r++) {
                int gr = row0 + w * 16 + quad * 4 + r;
                float v = e8[r];
                if (m16 < 4) el[gr * 4 + m16] = v;
                else         er[gr * 4 + (m16 - 4)] = v;
            }
        }
    }
}

// out[b][n][o] = x[row=n*2+b] @ W_dec + b_dec ; output dtype follows input dtype
__global__ __launch_bounds__(256) void k_dec(const float* __restrict__ x,
                                             const void* __restrict__ Wd,
                                             const void* __restrict__ bd,
                                             void* __restrict__ out,
                                             const int* __restrict__ flag) {
    const int isbf = flag[0];
    __shared__ float sW[HID * OUT_DIM];
    __shared__ float sB[OUT_DIM];
    int t = threadIdx.x;
    for (int i = t; i < HID * OUT_DIM; i += 256) sW[i] = ld(Wd, i, isbf);
    if (t < OUT_DIM) sB[t] = ld(bd, t, isbf);
    __syncthreads();
    int gid = blockIdx.x * 256 + t;
    if (gid >= ROWS * OUT_DIM) return;
    int row = gid >> 3, o = gid & 7;
    int n = row >> 1, b = row & 1;
    float acc = sB[o];
#pragma unroll
    for (int k = 0; k < HID; k++) acc += x[(size_t)row * HID + k] * sW[k * OUT_DIM + o];
    size_t oi = (size_t)(b * N_NODES + n) * OUT_DIM + o;
    if (isbf) ((unsigned short*)out)[oi] = f2us(acc);
    else      ((float*)out)[oi] = acc;
}

extern "C" void kernel_launch(void* const* d_in, const int* in_sizes, int n_in,
                              void* d_out, int out_size, void* d_ws, size_t ws_size,
                              hipStream_t stream) {
    const void* h     = d_in[0];
    const int*  ei    = (const int*)d_in[1];
    const void* W_enc = d_in[2];
    const void* b_enc = d_in[3];
    const void* W_gat = d_in[4];
    const void* a_l   = d_in[5];
    const void* a_r   = d_in[6];
    const void* b_gat = d_in[7];
    const void* W_res = d_in[8];
    const void* b_res = d_in[9];
    const void* W_dec = d_in[10];
    const void* b_dec = d_in[11];

    float* ws = (float*)d_ws;
    int*   flag     = (int*)(ws + WS_FLAG);
    float* x        = ws + WS_X;
    unsigned int* xb32  = (unsigned int*)(ws + WS_XB32);
    unsigned int* aggxb = (unsigned int*)(ws + WS_AGGXB);
    float* el       = ws + WS_EL;
    float* er       = ws + WS_ER;
    int*   deg      = (int*)(ws + WS_DEG);
    int*   rowstart = (int*)(ws + WS_ROWSTART);
    int*   cursor   = (int*)(ws + WS_CUR);
    int*   csrc     = (int*)(ws + WS_CSRC);
    unsigned short* WgBpk   = (unsigned short*)(ws + WS_WGBPK);
    unsigned short* WresBpk = (unsigned short*)(ws + WS_WRESBPK);
    unsigned short* Wx8pk   = (unsigned short*)(ws + WS_WX8PK);
    float* bgm      = ws + WS_BGM;

    const int* src = ei;
    const int* dst = ei + N_EDGES;

    k_sniff<<<1, 256, 0, stream>>>(h, flag);
    k_prep<<<18, 256, 0, stream>>>(W_gat, a_l, a_r, W_res, b_gat, flag, WgBpk, WresBpk, Wx8pk, bgm);
    k_enc<<<ROWS / 4, 256, 0, stream>>>(h, W_enc, b_enc, x, flag);

    hipMemsetAsync(deg, 0, N_NODES * sizeof(int), stream);
    k_hist<<<(N_EDGES + 255) / 256, 256, 0, stream>>>(dst, deg);
    k_scan<<<1, 1024, 0, stream>>>(deg, rowstart, cursor);
    k_scatter<<<(N_EDGES + 255) / 256, 256, 0, stream>>>(src, dst, cursor, csrc);

    k_el<<<ROWS / 64, 256, 0, stream>>>(x, Wx8pk, el, er, xb32);

    for (int r = 0; r < 2; r++) {
        k_agg<<<N_NODES, 256, 0, stream>>>(rowstart, csrc, el, er, xb32, aggxb);
        k_update<<<ROWS / 64, 256, 0, stream>>>(x, aggxb, WgBpk, WresBpk, Wx8pk, b_res, bgm,
                                                xb32, el, er, flag, r == 0 ? 1 : 0);
    }
    k_dec<<<(ROWS * OUT_DIM + 255) / 256, 256, 0, stream>>>(x, W_dec, b_dec, d_out, flag);
}

// Round 10
// 290.207 us; speedup vs baseline: 17.2014x; 1.0530x over previous
//
#include <hip/hip_runtime.h>
#include <hip/hip_bf16.h>

#define N_NODES 20000
#define N_EDGES 320000
#define BATCH 2
#define IN_DIM 32
#define HID 64
#define HEADS 4
#define OUT_DIM 8
#define ROWS (N_NODES * BATCH) /* 40000 */
#define SLOPE 0.2f

typedef __hip_bfloat16 bf16;
typedef short v8s __attribute__((ext_vector_type(8)));
typedef float v4f __attribute__((ext_vector_type(4)));

// ---- workspace layout (float slots) ----
#define WS_X        0         /* 2,560,000 floats (written only by final update) */
#define WS_XB32     2560000   /* 20000*64 u32: packed bf16 (b0,b1) x table */
#define WS_AGGXB    3840000   /* 20000*256 u32: packed normalized head-aggregates */
#define WS_EL       8960000   /* 160,000 */
#define WS_ER       9120000   /* 160,000 */
#define WS_DEG      9280000   /* 20,032 ints */
#define WS_ROWSTART 9300032   /* 20,032 ints (20001 used) */
#define WS_CUR      9320064   /* 20,032 ints */
#define WS_CSRC     9340096   /* 320,000 ints */
#define WS_WGBPK    9660096   /* 16384 u16 */
#define WS_WRESBPK  9668288   /* 4096 u16 */
#define WS_WX8PK    9670336   /* 1024 u16 */
#define WS_WENCBPK  9670848   /* 2048 u16 */
#define WS_BGM      9671872   /* 64 floats */
#define WS_END      9671936   /* ~38.7 MB */

__device__ __forceinline__ float us2f(unsigned short u) {
    union { unsigned int i; float f; } z; z.i = ((unsigned int)u) << 16; return z.f;
}
__device__ __forceinline__ float u2f_lo(unsigned int u) {
    union { unsigned int i; float f; } z; z.i = u << 16; return z.f;
}
__device__ __forceinline__ float u2f_hi(unsigned int u) {
    union { unsigned int i; float f; } z; z.i = u & 0xffff0000u; return z.f;
}
__device__ __forceinline__ unsigned short f2us(float f) {
    bf16 b = __float2bfloat16(f);
    return *(unsigned short*)&b;
}
__device__ __forceinline__ float ld(const void* p, int i, int isbf) {
    if (isbf) return us2f(((const unsigned short*)p)[i]);
    return ((const float*)p)[i];
}
__device__ __forceinline__ float lrexp(float v) {
    v = v > 0.f ? v : SLOPE * v;
    return __expf(fminf(v, 60.f));
}

// Inline bf16-vs-fp32 sniffer: sample 64 even 16-bit halves of h per wave.
// fp32 data -> mantissa garbage, P(exp in [100,150]) ~ 0.2; bf16 N(0,s) -> ~1.0.
__device__ __forceinline__ int sniff64(const void* h) {
    const unsigned short* u = (const unsigned short*)h;
    int lane = threadIdx.x & 63;
    unsigned short v = u[2 * lane];
    int ef = (v >> 7) & 0xFF;
    unsigned long long m = __ballot(ef >= 100 && ef <= 150);
    return __popcll(m) >= 48;
}

// Pack all B-operands into MFMA-fragment-native layout (one 16B load per frag).
__global__ __launch_bounds__(256) void k_prep(const void* __restrict__ h,
                                              const void* __restrict__ Wg,
                                              const void* __restrict__ al,
                                              const void* __restrict__ ar,
                                              const void* __restrict__ Wr,
                                              const void* __restrict__ We,
                                              const void* __restrict__ bg,
                                              unsigned short* __restrict__ WgBpk,
                                              unsigned short* __restrict__ WresBpk,
                                              unsigned short* __restrict__ Wx8pk,
                                              unsigned short* __restrict__ WencBpk,
                                              float* __restrict__ bgm) {
    const int isbf = sniff64(h);
    int t = threadIdx.x, b = blockIdx.x;
    if (b < 16) {
#pragma unroll
        for (int q = 0; q < 4; q++) {
            int idx = b * 1024 + q * 256 + t;
            int j = idx & 7, m16 = (idx >> 3) & 15, quad = (idx >> 7) & 3;
            int ks = (idx >> 9) & 1, ct = (idx >> 10) & 3, hh = (idx >> 12) & 3;
            int k = ks * 32 + quad * 8 + j;
            int c = hh * 64 + ct * 16 + m16;
            WgBpk[idx] = f2us(ld(Wg, k * 256 + c, isbf));
        }
    } else if (b == 16) {
#pragma unroll
        for (int q = 0; q < 4; q++) {
            int idx = q * 256 + t;
            int j = idx & 7, m16 = (idx >> 3) & 15, quad = (idx >> 7) & 3;
            int ks = (idx >> 9) & 1;
            int k = ks * 32 + quad * 8 + j;
            float v = 0.f;
            if (m16 < 8) {
                int hh = m16 & 3, lr = m16 >> 2;
                const void* a = lr ? ar : al;
                for (int d = 0; d < 64; d++)
                    v += ld(Wg, k * 256 + hh * 64 + d, isbf) * ld(a, hh * 64 + d, isbf);
            }
            Wx8pk[idx] = f2us(v);
        }
        // WencBpk: idx = (ct<<9)|(quad<<7)|(m16<<3)|j ; value We[k*64 + ct*16+m16], k=quad*8+j
#pragma unroll
        for (int q = 0; q < 8; q++) {
            int idx = q * 256 + t;
            int j = idx & 7, m16 = (idx >> 3) & 15, quad = (idx >> 7) & 3, ct = idx >> 9;
            int k = quad * 8 + j;
            WencBpk[idx] = f2us(ld(We, k * 64 + ct * 16 + m16, isbf));
        }
        if (t < 64) {
            float s = 0.f;
            for (int hh = 0; hh < 4; hh++) s += ld(bg, hh * 64 + t, isbf);
            bgm[t] = 0.25f * s;
        }
    } else {
#pragma unroll
        for (int q = 0; q < 16; q++) {
            int idx = q * 256 + t;
            int j = idx & 7, m16 = (idx >> 3) & 15, quad = (idx >> 7) & 3;
            int ks = (idx >> 9) & 1, ct = (idx >> 10) & 3;
            int k = ks * 32 + quad * 8 + j;
            WresBpk[idx] = f2us(ld(Wr, k * 64 + ct * 16 + m16, isbf));
        }
    }
}

// ---- CSR build ----
__global__ __launch_bounds__(256) void k_hist(const int* __restrict__ dst, int* __restrict__ deg) {
    int e = blockIdx.x * 256 + threadIdx.x;
    if (e < N_EDGES) atomicAdd(&deg[dst[e]], 1);
}

__global__ __launch_bounds__(1024) void k_scan(const int* __restrict__ deg,
                                               int* __restrict__ rowstart,
                                               int* __restrict__ cursor) {
    __shared__ int ssum[1024];
    int t = threadIdx.x;
    int base = t * 20;
    int local[20];
    int s = 0;
#pragma unroll
    for (int i = 0; i < 20; i++) {
        int v = (base + i < N_NODES) ? deg[base + i] : 0;
        local[i] = s;
        s += v;
    }
    ssum[t] = s;
    __syncthreads();
    for (int off = 1; off < 1024; off <<= 1) {
        int v = (t >= off) ? ssum[t - off] : 0;
        __syncthreads();
        if (t >= off) ssum[t] += v;
        __syncthreads();
    }
    int prev = (t == 0) ? 0 : ssum[t - 1];
#pragma unroll
    for (int i = 0; i < 20; i++) {
        if (base + i < N_NODES) {
            int v = prev + local[i];
            rowstart[base + i] = v;
            cursor[base + i] = v;
        }
    }
    if (t == 1023) rowstart[N_NODES] = ssum[1023];
}

__global__ __launch_bounds__(256) void k_scatter(const int* __restrict__ src,
                                                 const int* __restrict__ dst,
                                                 int* __restrict__ cursor,
                                                 int* __restrict__ csrc) {
    int e = blockIdx.x * 256 + threadIdx.x;
    if (e >= N_EDGES) return;
    int pos = atomicAdd(&cursor[dst[e]], 1);
    csrc[pos] = src[e];
}

// Fused encoder: xb32 (packed bf16 batch-pair x) + el/er, via one K=32 MFMA step.
// Block = 64 rows (32 nodes x 2 batches); wave w = rows w*16..+15.
__global__ __launch_bounds__(256) void k_enc2(const void* __restrict__ h,
                                              const unsigned short* __restrict__ WencBpk,
                                              const void* __restrict__ benc,
                                              const unsigned short* __restrict__ Wx8pk,
                                              unsigned int* __restrict__ xb32,
                                              float* __restrict__ el,
                                              float* __restrict__ er) {
    const int isbf = sniff64(h);
    __shared__ unsigned short sXb[64 * 64];
    int t = threadIdx.x;
    int w = t >> 6, lane = t & 63, quad = lane >> 4, m16 = lane & 15;
    int row0 = blockIdx.x * 64;
    int grow = row0 + w * 16 + m16;
    int n = grow >> 1, b = grow & 1;

    v8s Af;
    size_t hb = (size_t)(b * N_NODES + n) * IN_DIM + quad * 8;
    if (isbf) {
        Af = *(const v8s*)((const unsigned short*)h + hb);
    } else {
        const float4* hp = (const float4*)((const float*)h + hb);
        float4 xa = hp[0], xbv = hp[1];
        Af[0] = (short)f2us(xa.x);  Af[1] = (short)f2us(xa.y);
        Af[2] = (short)f2us(xa.z);  Af[3] = (short)f2us(xa.w);
        Af[4] = (short)f2us(xbv.x); Af[5] = (short)f2us(xbv.y);
        Af[6] = (short)f2us(xbv.z); Af[7] = (short)f2us(xbv.w);
    }

    v4f acc[4];
#pragma unroll
    for (int ct = 0; ct < 4; ct++) {
        v8s Bf = *(const v8s*)(WencBpk + ((ct << 9) | (quad << 7) | (m16 << 3)));
        acc[ct] = __builtin_amdgcn_mfma_f32_16x16x32_bf16(Af, Bf, (v4f)(0.f), 0, 0, 0);
    }

    // epilogue: bias, packed x table + LDS bf16 tile
#pragma unroll
    for (int ct = 0; ct < 4; ct++) {
        int col = ct * 16 + m16;
        float bv = ld(benc, col, isbf);
        float vr[4];
        int rloc0 = w * 16 + quad * 4;
#pragma unroll
        for (int r = 0; r < 4; r++) {
            vr[r] = acc[ct][r] + bv;
            sXb[(rloc0 + r) * 64 + col] = f2us(vr[r]);
        }
        int nd0 = (row0 + rloc0) >> 1;
        xb32[(size_t)nd0 * 64 + col] =
            (unsigned int)f2us(vr[0]) | ((unsigned int)f2us(vr[1]) << 16);
        xb32[(size_t)(nd0 + 1) * 64 + col] =
            (unsigned int)f2us(vr[2]) | ((unsigned int)f2us(vr[3]) << 16);
    }
    __syncthreads();
    v4f e8 = (v4f)(0.f);
#pragma unroll
    for (int ks = 0; ks < 2; ks++) {
        v8s Af2 = *(const v8s*)(sXb + (w * 16 + m16) * 64 + ks * 32 + quad * 8);
        v8s Bf = *(const v8s*)(Wx8pk + (((ks * 4 + quad) << 7) + (m16 << 3)));
        e8 = __builtin_amdgcn_mfma_f32_16x16x32_bf16(Af2, Bf, e8, 0, 0, 0);
    }
    if (m16 < 8) {
#pragma unroll
        for (int r = 0; r < 4; r++) {
            int gr = row0 + w * 16 + quad * 4 + r;
            float v = e8[r];
            if (m16 < 4) el[gr * 4 + m16] = v;
            else         er[gr * 4 + (m16 - 4)] = v;
        }
    }
}

// Edge phase: ONE WAVE per dst node (no barriers, no LDS). Lane = column.
// Per edge: 1 packed u32 gather + weight via lane-octet shfl broadcast.
__global__ __launch_bounds__(256) void k_agg(const int* __restrict__ rowstart,
                                             const int* __restrict__ csrc,
                                             const float* __restrict__ el,
                                             const float* __restrict__ er,
                                             const unsigned int* __restrict__ xb32,
                                             unsigned int* __restrict__ aggxb) {
    int t = threadIdx.x;
    int n = blockIdx.x * 4 + (t >> 6);
    int c = t & 63;
    int i8 = c & 7;                 // weight index i = b*4+h handled by this lane-octet slot
    float rv = er[n * 8 + i8];
    int beg = rowstart[n], end = rowstart[n + 1];
    float a[8] = {0.f, 0.f, 0.f, 0.f, 0.f, 0.f, 0.f, 0.f};
    float wss = 0.f;
    for (int p = beg; p < end; p++) {
        int s = csrc[p];
        float wt = lrexp(el[s * 8 + i8] + rv);
        wss += wt;
        unsigned int q = xb32[(size_t)s * 64 + c];
        float xlo = u2f_lo(q), xhi = u2f_hi(q);
#pragma unroll
        for (int i = 0; i < 8; i++) {
            float wi = __shfl(wt, i);
            a[i] += wi * ((i < 4) ? xlo : xhi);
        }
    }
    float vout[8];
#pragma unroll
    for (int i = 0; i < 8; i++) {
        float wsi = __shfl(wss, i);
        vout[i] = (end > beg) ? a[i] / (4.f * wsi) : 0.f;
    }
#pragma unroll
    for (int hh = 0; hh < 4; hh++)
        aggxb[(size_t)n * 256 + hh * 64 + c] =
            (unsigned int)f2us(vout[hh]) | ((unsigned int)f2us(vout[4 + hh]) << 16);
}

// Fused update: v = elu( sum_h(Ah_norm/4 @ Wg_h) + bgm + x @ W_res + b_res ).
// Residual x read from packed xb32. emit=1: write next xb32 + el/er. emit=0: write x fp32.
__global__ __launch_bounds__(256) void k_update(const void* __restrict__ h,
                                                float* __restrict__ x,
                                                const unsigned int* __restrict__ aggxb,
                                                const unsigned short* __restrict__ WgBpk,
                                                const unsigned short* __restrict__ WresBpk,
                                                const unsigned short* __restrict__ Wx8pk,
                                                const void* __restrict__ br,
                                                const float* __restrict__ bgm,
                                                unsigned int* __restrict__ xb32,
                                                float* __restrict__ el,
                                                float* __restrict__ er,
                                                int emit) {
    const int isbf = sniff64(h);
    __shared__ unsigned short sXb[64 * 64];
    int t = threadIdx.x;
    int w = t >> 6, lane = t & 63, quad = lane >> 4, m16 = lane & 15;
    int row0 = blockIdx.x * 64;
    int grow = row0 + w * 16 + m16;
    int nd = grow >> 1;
    unsigned sh = (grow & 1) * 16;

    v4f acc[4];
#pragma unroll
    for (int ct = 0; ct < 4; ct++) acc[ct] = (v4f)(0.f);

    // 4 head GEMMs from packed aggregates
#pragma unroll
    for (int hh = 0; hh < 4; hh++) {
#pragma unroll
        for (int ks = 0; ks < 2; ks++) {
            const uint4* ap = (const uint4*)(aggxb + (size_t)nd * 256 + hh * 64 + ks * 32 + quad * 8);
            uint4 qa = ap[0], qb = ap[1];
            v8s Af;
            Af[0] = (short)((qa.x >> sh) & 0xffffu);
            Af[1] = (short)((qa.y >> sh) & 0xffffu);
            Af[2] = (short)((qa.z >> sh) & 0xffffu);
            Af[3] = (short)((qa.w >> sh) & 0xffffu);
            Af[4] = (short)((qb.x >> sh) & 0xffffu);
            Af[5] = (short)((qb.y >> sh) & 0xffffu);
            Af[6] = (short)((qb.z >> sh) & 0xffffu);
            Af[7] = (short)((qb.w >> sh) & 0xffffu);
#pragma unroll
            for (int ct = 0; ct < 4; ct++) {
                v8s Bf = *(const v8s*)(WgBpk + ((hh << 12) | (ct << 10) | (ks << 9) | (quad << 7) | (m16 << 3)));
                acc[ct] = __builtin_amdgcn_mfma_f32_16x16x32_bf16(Af, Bf, acc[ct], 0, 0, 0);
            }
        }
    }
    // residual GEMM from packed x
#pragma unroll
    for (int ks = 0; ks < 2; ks++) {
        const uint4* xp = (const uint4*)(xb32 + (size_t)nd * 64 + ks * 32 + quad * 8);
        uint4 qa = xp[0], qb = xp[1];
        v8s Af;
        Af[0] = (short)((qa.x >> sh) & 0xffffu);
        Af[1] = (short)((qa.y >> sh) & 0xffffu);
        Af[2] = (short)((qa.z >> sh) & 0xffffu);
        Af[3] = (short)((qa.w >> sh) & 0xffffu);
        Af[4] = (short)((qb.x >> sh) & 0xffffu);
        Af[5] = (short)((qb.y >> sh) & 0xffffu);
        Af[6] = (short)((qb.z >> sh) & 0xffffu);
        Af[7] = (short)((qb.w >> sh) & 0xffffu);
#pragma unroll
        for (int ct = 0; ct < 4; ct++) {
            v8s Bf = *(const v8s*)(WresBpk + ((ct << 10) | (ks << 9) | (quad << 7) | (m16 << 3)));
            acc[ct] = __builtin_amdgcn_mfma_f32_16x16x32_bf16(Af, Bf, acc[ct], 0, 0, 0);
        }
    }

    if (emit) __syncthreads();   // WAR: all xb32 reads complete before rewrite

#pragma unroll
    for (int ct = 0; ct < 4; ct++) {
        int col = ct * 16 + m16;
        float bv = ld(br, col, isbf) + bgm[col];
        float vr[4];
        int rloc0 = w * 16 + quad * 4;
#pragma unroll
        for (int r = 0; r < 4; r++) {
            float v = acc[ct][r] + bv;
            v = v > 0.f ? v : expm1f(v);
            vr[r] = v;
            if (emit) sXb[(rloc0 + r) * 64 + col] = f2us(v);
            else      x[(size_t)(row0 + rloc0 + r) * 64 + col] = v;
        }
        if (emit) {
            int nd0 = (row0 + rloc0) >> 1;
            xb32[(size_t)nd0 * 64 + col] =
                (unsigned int)f2us(vr[0]) | ((unsigned int)f2us(vr[1]) << 16);
            xb32[(size_t)(nd0 + 1) * 64 + col] =
                (unsigned int)f2us(vr[2]) | ((unsigned int)f2us(vr[3]) << 16);
        }
    }
    if (emit) {
        __syncthreads();
        v4f e8 = (v4f)(0.f);
#pragma unroll
        for (int ks = 0; ks < 2; ks++) {
            v8s Af = *(const v8s*)(sXb + (w * 16 + m16) * 64 + ks * 32 + quad * 8);
            v8s Bf = *(const v8s*)(Wx8pk + (((ks * 4 + quad) << 7) + (m16 << 3)));
            e8 = __builtin_amdgcn_mfma_f32_16x16x32_bf16(Af, Bf, e8, 0, 0, 0);
        }
        if (m16 < 8) {
#pragma unroll
            for (int r = 0; r < 4; r++) {
                int gr = row0 + w * 16 + quad * 4 + r;
                float v = e8[r];
                if (m16 < 4) el[gr * 4 + m16] = v;
                else         er[gr * 4 + (m16 - 4)] = v;
            }
        }
    }
}

// out[b][n][o] = x[row=n*2+b] @ W_dec + b_dec ; output dtype follows input dtype
__global__ __launch_bounds__(256) void k_dec(const void* __restrict__ h,
                                             const float* __restrict__ x,
                                             const void* __restrict__ Wd,
                                             const void* __restrict__ bd,
                                             void* __restrict__ out) {
    const int isbf = sniff64(h);
    __shared__ float sW[HID * OUT_DIM];
    __shared__ float sB[OUT_DIM];
    int t = threadIdx.x;
    for (int i = t; i < HID * OUT_DIM; i += 256) sW[i] = ld(Wd, i, isbf);
    if (t < OUT_DIM) sB[t] = ld(bd, t, isbf);
    __syncthreads();
    int gid = blockIdx.x * 256 + t;
    if (gid >= ROWS * OUT_DIM) return;
    int row = gid >> 3, o = gid & 7;
    int n = row >> 1, b = row & 1;
    float acc = sB[o];
#pragma unroll
    for (int k = 0; k < HID; k++) acc += x[(size_t)row * HID + k] * sW[k * OUT_DIM + o];
    size_t oi = (size_t)(b * N_NODES + n) * OUT_DIM + o;
    if (isbf) ((unsigned short*)out)[oi] = f2us(acc);
    else      ((float*)out)[oi] = acc;
}

extern "C" void kernel_launch(void* const* d_in, const int* in_sizes, int n_in,
                              void* d_out, int out_size, void* d_ws, size_t ws_size,
                              hipStream_t stream) {
    const void* h     = d_in[0];
    const int*  ei    = (const int*)d_in[1];
    const void* W_enc = d_in[2];
    const void* b_enc = d_in[3];
    const void* W_gat = d_in[4];
    const void* a_l   = d_in[5];
    const void* a_r   = d_in[6];
    const void* b_gat = d_in[7];
    const void* W_res = d_in[8];
    const void* b_res = d_in[9];
    const void* W_dec = d_in[10];
    const void* b_dec = d_in[11];

    float* ws = (float*)d_ws;
    float* x        = ws + WS_X;
    unsigned int* xb32  = (unsigned int*)(ws + WS_XB32);
    unsigned int* aggxb = (unsigned int*)(ws + WS_AGGXB);
    float* el       = ws + WS_EL;
    float* er       = ws + WS_ER;
    int*   deg      = (int*)(ws + WS_DEG);
    int*   rowstart = (int*)(ws + WS_ROWSTART);
    int*   cursor   = (int*)(ws + WS_CUR);
    int*   csrc     = (int*)(ws + WS_CSRC);
    unsigned short* WgBpk   = (unsigned short*)(ws + WS_WGBPK);
    unsigned short* WresBpk = (unsigned short*)(ws + WS_WRESBPK);
    unsigned short* Wx8pk   = (unsigned short*)(ws + WS_WX8PK);
    unsigned short* WencBpk = (unsigned short*)(ws + WS_WENCBPK);
    float* bgm      = ws + WS_BGM;

    const int* src = ei;
    const int* dst = ei + N_EDGES;

    hipMemsetAsync(deg, 0, N_NODES * sizeof(int), stream);
    k_prep<<<18, 256, 0, stream>>>(h, W_gat, a_l, a_r, W_res, W_enc, b_gat,
                                   WgBpk, WresBpk, Wx8pk, WencBpk, bgm);
    k_hist<<<(N_EDGES + 255) / 256, 256, 0, stream>>>(dst, deg);
    k_scan<<<1, 1024, 0, stream>>>(deg, rowstart, cursor);
    k_scatter<<<(N_EDGES + 255) / 256, 256, 0, stream>>>(src, dst, cursor, csrc);

    k_enc2<<<ROWS / 64, 256, 0, stream>>>(h, WencBpk, b_enc, Wx8pk, xb32, el, er);

    for (int r = 0; r < 2; r++) {
        k_agg<<<N_NODES / 4, 256, 0, stream>>>(rowstart, csrc, el, er, xb32, aggxb);
        k_update<<<ROWS / 64, 256, 0, stream>>>(h, x, aggxb, WgBpk, WresBpk, Wx8pk,
                                                b_res, bgm, xb32, el, er, r == 0 ? 1 : 0);
    }
    k_dec<<<(ROWS * OUT_DIM + 255) / 256, 256, 0, stream>>>(h, x, W_dec, b_dec, d_out);
}